// Round 1
// baseline (2027.761 us; speedup 1.0000x reference)
//
#include <hip/hip_runtime.h>
#include <math.h>

#define S_LEN 2048
#define NBATCH 2
#define DMODEL 1024
#define PDIM 4480   // 2*2048 + 2*128 + 3*32 + 32
#define DI 2048
#define NH 32
#define HD 64
#define DS 128
#define NA 32
// proj column offsets
#define OFF_Z 0
#define OFF_V 2048
#define OFF_B 4096
#define OFF_C 4224
#define OFF_DT 4352
#define OFF_A 4384
#define OFF_TRAP 4416
#define OFF_ANG 4448

__device__ __forceinline__ float softplus_f(float x) {
    return x > 20.f ? x : log1pf(expf(x));
}

// ---------------------------------------------------------------------------
// GEMM NT: C[m][n] = sum_k A[m*K+k] * B[n*K+k]   (both operands K-contiguous)
// 128x128 tile, BK=16, 256 threads, 8x8 per thread. fp32.
// ---------------------------------------------------------------------------
__global__ __launch_bounds__(256, 2)
void sgemm_nt(const float* __restrict__ A, const float* __restrict__ B,
              float* __restrict__ C, int M, int N, int K) {
    const int BM = 128, BN = 128, BK = 16;
    __shared__ float As[BK][BM + 4];
    __shared__ float Bs[BK][BN + 4];
    int tid = threadIdx.x;
    int nb = N / BN;
    int bx = blockIdx.x % nb;
    int by = blockIdx.x / nb;

    int lr = tid >> 2;          // 0..63
    int lc = (tid & 3) << 2;    // 0,4,8,12

    const float* Ab = A + (size_t)(by * BM + lr) * K + lc;
    const float* Bb = B + (size_t)(bx * BN + lr) * K + lc;

    int tx = tid & 15, ty = tid >> 4;
    float acc[8][8];
#pragma unroll
    for (int i = 0; i < 8; ++i)
#pragma unroll
        for (int j = 0; j < 8; ++j) acc[i][j] = 0.f;

    for (int k0 = 0; k0 < K; k0 += BK) {
        float4 a0 = *(const float4*)(Ab + k0);
        float4 a1 = *(const float4*)(Ab + (size_t)64 * K + k0);
        float4 b0 = *(const float4*)(Bb + k0);
        float4 b1 = *(const float4*)(Bb + (size_t)64 * K + k0);
        __syncthreads();
        As[lc + 0][lr] = a0.x; As[lc + 1][lr] = a0.y; As[lc + 2][lr] = a0.z; As[lc + 3][lr] = a0.w;
        As[lc + 0][lr + 64] = a1.x; As[lc + 1][lr + 64] = a1.y; As[lc + 2][lr + 64] = a1.z; As[lc + 3][lr + 64] = a1.w;
        Bs[lc + 0][lr] = b0.x; Bs[lc + 1][lr] = b0.y; Bs[lc + 2][lr] = b0.z; Bs[lc + 3][lr] = b0.w;
        Bs[lc + 0][lr + 64] = b1.x; Bs[lc + 1][lr + 64] = b1.y; Bs[lc + 2][lr + 64] = b1.z; Bs[lc + 3][lr + 64] = b1.w;
        __syncthreads();
#pragma unroll
        for (int k = 0; k < BK; ++k) {
            float4 aA = *(const float4*)&As[k][ty * 8];
            float4 aB = *(const float4*)&As[k][ty * 8 + 4];
            float4 bA = *(const float4*)&Bs[k][tx * 8];
            float4 bB = *(const float4*)&Bs[k][tx * 8 + 4];
            float av[8] = {aA.x, aA.y, aA.z, aA.w, aB.x, aB.y, aB.z, aB.w};
            float bv[8] = {bA.x, bA.y, bA.z, bA.w, bB.x, bB.y, bB.z, bB.w};
#pragma unroll
            for (int i = 0; i < 8; ++i)
#pragma unroll
                for (int j = 0; j < 8; ++j) acc[i][j] += av[i] * bv[j];
        }
    }
#pragma unroll
    for (int i = 0; i < 8; ++i) {
        size_t row = (size_t)(by * BM + ty * 8 + i);
        float4 o0 = {acc[i][0], acc[i][1], acc[i][2], acc[i][3]};
        float4 o1 = {acc[i][4], acc[i][5], acc[i][6], acc[i][7]};
        *(float4*)(C + row * N + bx * BN + tx * 8) = o0;
        *(float4*)(C + row * N + bx * BN + tx * 8 + 4) = o1;
    }
}

// ---------------------------------------------------------------------------
// Phase cumsum + cos/sin. grid = NBATCH*NA blocks, 256 threads, 8 elems each.
// ---------------------------------------------------------------------------
__global__ __launch_bounds__(256)
void phase_kernel(const float* __restrict__ proj, float* __restrict__ cosb,
                  float* __restrict__ sinb) {
    int b = blockIdx.x >> 5;
    int j = blockIdx.x & 31;
    int tid = threadIdx.x;
    __shared__ float part[256];
    float v[8];
    float run = 0.f;
#pragma unroll
    for (int e = 0; e < 8; ++e) {
        int s = tid * 8 + e;
        v[e] = proj[((size_t)(b * S_LEN + s)) * PDIM + OFF_ANG + j];
        run += v[e];
    }
    part[tid] = run;
    __syncthreads();
    for (int off = 1; off < 256; off <<= 1) {
        float add = (tid >= off) ? part[tid - off] : 0.f;
        __syncthreads();
        part[tid] += add;
        __syncthreads();
    }
    float acc = (tid > 0) ? part[tid - 1] : 0.f;
#pragma unroll
    for (int e = 0; e < 8; ++e) {
        acc += v[e];  // inclusive cumsum
        int s = tid * 8 + e;
        size_t o = ((size_t)(b * S_LEN + s)) * NA + j;
        cosb[o] = cosf(acc);
        sinb[o] = sinf(acc);
    }
}

// ---------------------------------------------------------------------------
// Per-(b,s) prep: RMSNorm B/C (+rotate the norm part), per-head scalars.
// grid = NBATCH*S_LEN blocks, 128 threads.
// ---------------------------------------------------------------------------
__global__ __launch_bounds__(128)
void prep_kernel(const float* __restrict__ proj, const float* __restrict__ dt_bias,
                 const float* __restrict__ Bw, const float* __restrict__ Cw,
                 const float* __restrict__ cosb, const float* __restrict__ sinb,
                 float* __restrict__ Bn, float* __restrict__ Cn,
                 float* __restrict__ alpha, float* __restrict__ beta,
                 float* __restrict__ gamma) {
    size_t row = blockIdx.x;
    int b = (int)(row >> 11);
    int s = (int)(row & 2047);
    int n = threadIdx.x;
    const float* pr = proj + row * PDIM;
    float vB = pr[OFF_B + n];
    float vC = pr[OFF_C + n];
    float sB = vB * vB, sC = vC * vC;
#pragma unroll
    for (int off = 32; off >= 1; off >>= 1) {
        sB += __shfl_xor(sB, off);
        sC += __shfl_xor(sC, off);
    }
    __shared__ float redB[2], redC[2];
    if ((n & 63) == 0) { redB[n >> 6] = sB; redC[n >> 6] = sC; }
    __syncthreads();
    float rB = sqrtf((redB[0] + redB[1]) * (1.f / 128.f) + 1e-5f);
    float rC = sqrtf((redC[0] + redC[1]) * (1.f / 128.f) + 1e-5f);
    float bn = vB / rB * Bw[n];
    float cn = vC / rC * Cw[n];
    float bp = __shfl_xor(bn, 1);
    float cp = __shfl_xor(cn, 1);
    float ob = bn, oc = cn;
    if (n < 64) {
        float c = cosb[row * NA + (n >> 1)];
        float sn_ = sinb[row * NA + (n >> 1)];
        if ((n & 1) == 0) { ob = bn * c - bp * sn_; oc = cn * c - cp * sn_; }
        else              { ob = bp * sn_ + bn * c; oc = cp * sn_ + cn * c; }
    }
    Bn[row * DS + n] = ob;
    Cn[row * DS + n] = oc;
    if (n < NH) {
        int h = n;
        float dtv = softplus_f(pr[OFF_DT + h] + dt_bias[h]);
        float Av = -fmaxf(softplus_f(pr[OFF_A + h]), 1e-4f);
        float trap = 1.f / (1.f + expf(-pr[OFF_TRAP + h]));
        float al = expf(Av * dtv);
        size_t o = ((size_t)(b * NH + h)) * S_LEN + s;
        alpha[o] = al;
        beta[o] = (1.f - trap) * dtv * al;
        gamma[o] = trap * dtv;
    }
}

// ---------------------------------------------------------------------------
// Sequential scan. grid = NBATCH*NH*4 = 256 blocks (one n-slice of 32 each),
// 256 threads: p = tid>>2 (0..63), sub = tid&3 owns 8 n's. y via atomicAdd.
// ---------------------------------------------------------------------------
struct SlotT { float kc[32], qc[32], cs[16], sn[16], v[64], abg[3], pad; };

__global__ __launch_bounds__(256)
void scan_kernel(const float* __restrict__ proj, const float* __restrict__ Bn,
                 const float* __restrict__ Cn, const float* __restrict__ cosb,
                 const float* __restrict__ sinb, const float* __restrict__ alpha_,
                 const float* __restrict__ beta_, const float* __restrict__ gamma_,
                 const float* __restrict__ B_bias, const float* __restrict__ C_bias,
                 const float* __restrict__ D_param, float* __restrict__ y) {
    __shared__ SlotT slot[2];
    float* slotf = (float*)slot;
    const int SLOTF = sizeof(SlotT) / 4;  // 164
    int blk = blockIdx.x;
    int sl = blk & 3;
    int h = (blk >> 2) & 31;
    int b = blk >> 7;
    int tid = threadIdx.x;
    int p = tid >> 2, sub = tid & 3, nl = sub * 8;

    float biasB[8], biasC[8];
#pragma unroll
    for (int j = 0; j < 8; ++j) {
        biasB[j] = B_bias[h * DS + sl * 32 + nl + j];
        biasC[j] = C_bias[h * DS + sl * 32 + nl + j];
    }
    float Dp = D_param[h];

    size_t rowb = (size_t)b * S_LEN;
    const float* g = nullptr;
    size_t gstep = 0;
    int ldso = 0;
    if (tid < 32)       { ldso = tid;              g = Bn + rowb * DS + sl * 32 + tid;              gstep = DS; }
    else if (tid < 64)  { ldso = tid;              g = Cn + rowb * DS + sl * 32 + (tid - 32);       gstep = DS; }
    else if (tid < 80)  { if (sl < 2) { ldso = 64 + (tid - 64); g = cosb + rowb * NA + sl * 16 + (tid - 64); gstep = NA; } }
    else if (tid < 96)  { if (sl < 2) { ldso = 80 + (tid - 80); g = sinb + rowb * NA + sl * 16 + (tid - 80); gstep = NA; } }
    else if (tid < 160) { ldso = 96 + (tid - 96);  g = proj + rowb * PDIM + OFF_V + h * HD + (tid - 96); gstep = PDIM; }
    else if (tid == 160){ ldso = 160; g = alpha_ + ((size_t)(b * NH + h)) * S_LEN; gstep = 1; }
    else if (tid == 161){ ldso = 161; g = beta_  + ((size_t)(b * NH + h)) * S_LEN; gstep = 1; }
    else if (tid == 162){ ldso = 162; g = gamma_ + ((size_t)(b * NH + h)) * S_LEN; gstep = 1; }

    float st[8] = {0.f, 0.f, 0.f, 0.f, 0.f, 0.f, 0.f, 0.f};
    float kprev[8] = {0.f, 0.f, 0.f, 0.f, 0.f, 0.f, 0.f, 0.f};
    float vprev = 0.f;
    float r = g ? g[0] : 0.f;

    for (int t = 0; t < S_LEN; ++t) {
        if (g) slotf[(t & 1) * SLOTF + ldso] = r;
        __syncthreads();
        if (g && t + 1 < S_LEN) r = g[(size_t)(t + 1) * gstep];  // prefetch next step
        const float* sp_ = slotf + (t & 1) * SLOTF;
        float al = sp_[160], be = sp_[161], ga = sp_[162];
        float vp = sp_[96 + p];
        float k8[8], q8[8];
        if (sl < 2) {
#pragma unroll
            for (int a = 0; a < 4; ++a) {
                float c = sp_[64 + (nl >> 1) + a];
                float sv = sp_[80 + (nl >> 1) + a];
                float e = biasB[2 * a], o = biasB[2 * a + 1];
                k8[2 * a]     = sp_[nl + 2 * a]     + e * c - o * sv;
                k8[2 * a + 1] = sp_[nl + 2 * a + 1] + e * sv + o * c;
                e = biasC[2 * a]; o = biasC[2 * a + 1];
                q8[2 * a]     = sp_[32 + nl + 2 * a]     + e * c - o * sv;
                q8[2 * a + 1] = sp_[32 + nl + 2 * a + 1] + e * sv + o * c;
            }
        } else {
#pragma unroll
            for (int j = 0; j < 8; ++j) {
                k8[j] = sp_[nl + j] + biasB[j];
                q8[j] = sp_[32 + nl + j] + biasC[j];
            }
        }
        float bv = be * vprev, gv = ga * vp;
        float ys = 0.f;
#pragma unroll
        for (int j = 0; j < 8; ++j) {
            float sv2 = al * st[j] + bv * kprev[j];
            sv2 += gv * k8[j];
            st[j] = sv2;
            ys += sv2 * q8[j];
        }
        ys += __shfl_xor(ys, 1);
        ys += __shfl_xor(ys, 2);
        if (sub == 0) {
            float yv = ys + ((sl == 0) ? Dp * vp : 0.f);
            atomicAdd(&y[(rowb + t) * DI + h * HD + p], yv);
        }
#pragma unroll
        for (int j = 0; j < 8; ++j) kprev[j] = k8[j];
        vprev = vp;
    }
}

// ---------------------------------------------------------------------------
// y RMSNorm * out_norm_w * silu(z), in place. grid = NBATCH*S_LEN, 256 thr.
// ---------------------------------------------------------------------------
__global__ __launch_bounds__(256)
void ynorm_kernel(float* __restrict__ y, const float* __restrict__ proj,
                  const float* __restrict__ w) {
    size_t row = blockIdx.x;
    int tid = threadIdx.x;
    float* yr = y + row * (size_t)DI;
    float4 v0 = *(const float4*)(yr + tid * 8);
    float4 v1 = *(const float4*)(yr + tid * 8 + 4);
    float ss = v0.x * v0.x + v0.y * v0.y + v0.z * v0.z + v0.w * v0.w +
               v1.x * v1.x + v1.y * v1.y + v1.z * v1.z + v1.w * v1.w;
#pragma unroll
    for (int off = 32; off >= 1; off >>= 1) ss += __shfl_xor(ss, off);
    __shared__ float red[4];
    if ((tid & 63) == 0) red[tid >> 6] = ss;
    __syncthreads();
    float tot = red[0] + red[1] + red[2] + red[3];
    float rinv = 1.f / sqrtf(tot * (1.f / 2048.f) + 1e-5f);
    const float* zr = proj + row * (size_t)PDIM + OFF_Z;
    float4 z0 = *(const float4*)(zr + tid * 8);
    float4 z1 = *(const float4*)(zr + tid * 8 + 4);
    float4 w0 = *(const float4*)(w + tid * 8);
    float4 w1 = *(const float4*)(w + tid * 8 + 4);
    float yv[8] = {v0.x, v0.y, v0.z, v0.w, v1.x, v1.y, v1.z, v1.w};
    float zv[8] = {z0.x, z0.y, z0.z, z0.w, z1.x, z1.y, z1.z, z1.w};
    float wv[8] = {w0.x, w0.y, w0.z, w0.w, w1.x, w1.y, w1.z, w1.w};
    float ov[8];
#pragma unroll
    for (int e = 0; e < 8; ++e) {
        float sil = zv[e] / (1.f + expf(-zv[e]));
        ov[e] = yv[e] * rinv * wv[e] * sil;
    }
    float4 o0 = {ov[0], ov[1], ov[2], ov[3]};
    float4 o1 = {ov[4], ov[5], ov[6], ov[7]};
    *(float4*)(yr + tid * 8) = o0;
    *(float4*)(yr + tid * 8 + 4) = o1;
}

// ---------------------------------------------------------------------------
extern "C" void kernel_launch(void* const* d_in, const int* in_sizes, int n_in,
                              void* d_out, int out_size, void* d_ws, size_t ws_size,
                              hipStream_t stream) {
    const float* x         = (const float*)d_in[0];
    const float* W_in      = (const float*)d_in[1];
    const float* dt_bias   = (const float*)d_in[2];
    const float* B_norm_w  = (const float*)d_in[3];
    const float* C_norm_w  = (const float*)d_in[4];
    const float* B_bias    = (const float*)d_in[5];
    const float* C_bias    = (const float*)d_in[6];
    const float* D_param   = (const float*)d_in[7];
    const float* out_norm_w= (const float*)d_in[8];
    const float* W_out     = (const float*)d_in[9];
    float* out = (float*)d_out;

    const size_t M = (size_t)NBATCH * S_LEN;  // 4096
    float* ws = (float*)d_ws;
    size_t off = 0;
    float* proj = ws + off;  off += M * PDIM;       // 18,350,080
    float* cosb = ws + off;  off += M * NA;
    float* sinb = ws + off;  off += M * NA;
    float* Bn   = ws + off;  off += M * DS;
    float* Cn   = ws + off;  off += M * DS;
    float* alpha= ws + off;  off += (size_t)NBATCH * NH * S_LEN;
    float* beta = ws + off;  off += (size_t)NBATCH * NH * S_LEN;
    float* gamma= ws + off;  off += (size_t)NBATCH * NH * S_LEN;
    float* y    = ws + off;  off += M * DI;

    // 1) proj = x @ W_in^T  (M=4096, N=4480, K=1024)
    sgemm_nt<<<dim3((PDIM / 128) * (M / 128)), 256, 0, stream>>>(x, W_in, proj, (int)M, PDIM, DMODEL);
    // 2) phase cumsum -> cos/sin
    phase_kernel<<<dim3(NBATCH * NA), 256, 0, stream>>>(proj, cosb, sinb);
    // 3) per-row prep
    prep_kernel<<<dim3((int)M), 128, 0, stream>>>(proj, dt_bias, B_norm_w, C_norm_w,
                                                  cosb, sinb, Bn, Cn, alpha, beta, gamma);
    // 4) zero y, then scan
    hipMemsetAsync(y, 0, M * DI * sizeof(float), stream);
    scan_kernel<<<dim3(NBATCH * NH * 4), 256, 0, stream>>>(proj, Bn, Cn, cosb, sinb,
                                                           alpha, beta, gamma,
                                                           B_bias, C_bias, D_param, y);
    // 5) y = rmsnorm(y)*w*silu(z), in place
    ynorm_kernel<<<dim3((int)M), 256, 0, stream>>>(y, proj, out_norm_w);
    // 6) out = y @ W_out^T  (M=4096, N=1024, K=2048)
    sgemm_nt<<<dim3((DMODEL / 128) * (M / 128)), 256, 0, stream>>>(y, W_out, out, (int)M, DMODEL, DI);
}

// Round 2
// 1051.299 us; speedup vs baseline: 1.9288x; 1.9288x over previous
//
#include <hip/hip_runtime.h>
#include <math.h>

#define S_LEN 2048
#define NBATCH 2
#define DMODEL 1024
#define PDIM 4480   // 2*2048 + 2*128 + 3*32 + 32
#define DI 2048
#define NH 32
#define HD 64
#define DS 128
#define NA 32
#define CHK 64
#define NC (S_LEN / CHK)   // 32 chunks per batch
// proj column offsets
#define OFF_Z 0
#define OFF_V 2048
#define OFF_B 4096
#define OFF_C 4224
#define OFF_DT 4352
#define OFF_A 4384
#define OFF_TRAP 4416
#define OFF_ANG 4448

__device__ __forceinline__ float softplus_f(float x) {
    return x > 20.f ? x : log1pf(expf(x));
}

// ---------------------------------------------------------------------------
// GEMM NT: C[m][n] = sum_k A[m*K+k] * B[n*K+k]
// ---------------------------------------------------------------------------
__global__ __launch_bounds__(256, 2)
void sgemm_nt(const float* __restrict__ A, const float* __restrict__ B,
              float* __restrict__ C, int M, int N, int K) {
    const int BM = 128, BN = 128, BK = 16;
    __shared__ float As[BK][BM + 4];
    __shared__ float Bs[BK][BN + 4];
    int tid = threadIdx.x;
    int nb = N / BN;
    int bx = blockIdx.x % nb;
    int by = blockIdx.x / nb;

    int lr = tid >> 2;
    int lc = (tid & 3) << 2;

    const float* Ab = A + (size_t)(by * BM + lr) * K + lc;
    const float* Bb = B + (size_t)(bx * BN + lr) * K + lc;

    int tx = tid & 15, ty = tid >> 4;
    float acc[8][8];
#pragma unroll
    for (int i = 0; i < 8; ++i)
#pragma unroll
        for (int j = 0; j < 8; ++j) acc[i][j] = 0.f;

    for (int k0 = 0; k0 < K; k0 += BK) {
        float4 a0 = *(const float4*)(Ab + k0);
        float4 a1 = *(const float4*)(Ab + (size_t)64 * K + k0);
        float4 b0 = *(const float4*)(Bb + k0);
        float4 b1 = *(const float4*)(Bb + (size_t)64 * K + k0);
        __syncthreads();
        As[lc + 0][lr] = a0.x; As[lc + 1][lr] = a0.y; As[lc + 2][lr] = a0.z; As[lc + 3][lr] = a0.w;
        As[lc + 0][lr + 64] = a1.x; As[lc + 1][lr + 64] = a1.y; As[lc + 2][lr + 64] = a1.z; As[lc + 3][lr + 64] = a1.w;
        Bs[lc + 0][lr] = b0.x; Bs[lc + 1][lr] = b0.y; Bs[lc + 2][lr] = b0.z; Bs[lc + 3][lr] = b0.w;
        Bs[lc + 0][lr + 64] = b1.x; Bs[lc + 1][lr + 64] = b1.y; Bs[lc + 2][lr + 64] = b1.z; Bs[lc + 3][lr + 64] = b1.w;
        __syncthreads();
#pragma unroll
        for (int k = 0; k < BK; ++k) {
            float4 aA = *(const float4*)&As[k][ty * 8];
            float4 aB = *(const float4*)&As[k][ty * 8 + 4];
            float4 bA = *(const float4*)&Bs[k][tx * 8];
            float4 bB = *(const float4*)&Bs[k][tx * 8 + 4];
            float av[8] = {aA.x, aA.y, aA.z, aA.w, aB.x, aB.y, aB.z, aB.w};
            float bv[8] = {bA.x, bA.y, bA.z, bA.w, bB.x, bB.y, bB.z, bB.w};
#pragma unroll
            for (int i = 0; i < 8; ++i)
#pragma unroll
                for (int j = 0; j < 8; ++j) acc[i][j] += av[i] * bv[j];
        }
    }
#pragma unroll
    for (int i = 0; i < 8; ++i) {
        size_t row = (size_t)(by * BM + ty * 8 + i);
        float4 o0 = {acc[i][0], acc[i][1], acc[i][2], acc[i][3]};
        float4 o1 = {acc[i][4], acc[i][5], acc[i][6], acc[i][7]};
        *(float4*)(C + row * N + bx * BN + tx * 8) = o0;
        *(float4*)(C + row * N + bx * BN + tx * 8 + 4) = o1;
    }
}

// ---------------------------------------------------------------------------
// Phase cumsum + cos/sin. grid = NBATCH*NA, 256 threads, 8 elems each.
// ---------------------------------------------------------------------------
__global__ __launch_bounds__(256)
void phase_kernel(const float* __restrict__ proj, float* __restrict__ cosb,
                  float* __restrict__ sinb) {
    int b = blockIdx.x >> 5;
    int j = blockIdx.x & 31;
    int tid = threadIdx.x;
    __shared__ float part[256];
    float v[8];
    float run = 0.f;
#pragma unroll
    for (int e = 0; e < 8; ++e) {
        int s = tid * 8 + e;
        v[e] = proj[((size_t)(b * S_LEN + s)) * PDIM + OFF_ANG + j];
        run += v[e];
    }
    part[tid] = run;
    __syncthreads();
    for (int off = 1; off < 256; off <<= 1) {
        float add = (tid >= off) ? part[tid - off] : 0.f;
        __syncthreads();
        part[tid] += add;
        __syncthreads();
    }
    float acc = (tid > 0) ? part[tid - 1] : 0.f;
#pragma unroll
    for (int e = 0; e < 8; ++e) {
        acc += v[e];
        int s = tid * 8 + e;
        size_t o = ((size_t)(b * S_LEN + s)) * NA + j;
        cosb[o] = cosf(acc);
        sinb[o] = sinf(acc);
    }
}

// ---------------------------------------------------------------------------
// Per-(b,s) prep: RMSNorm B/C (rotate norm part), per-head ld/w/pu scalars.
// ---------------------------------------------------------------------------
__global__ __launch_bounds__(128)
void prep_kernel(const float* __restrict__ proj, const float* __restrict__ dt_bias,
                 const float* __restrict__ Bw, const float* __restrict__ Cw,
                 const float* __restrict__ cosb, const float* __restrict__ sinb,
                 float* __restrict__ Bn, float* __restrict__ Cn,
                 float* __restrict__ ldb, float* __restrict__ wbuf,
                 float* __restrict__ pubuf) {
    size_t row = blockIdx.x;
    int b = (int)(row >> 11);
    int s = (int)(row & 2047);
    int n = threadIdx.x;
    const float* pr = proj + row * PDIM;
    float vB = pr[OFF_B + n];
    float vC = pr[OFF_C + n];
    float sB = vB * vB, sC = vC * vC;
#pragma unroll
    for (int off = 32; off >= 1; off >>= 1) {
        sB += __shfl_xor(sB, off);
        sC += __shfl_xor(sC, off);
    }
    __shared__ float redB[2], redC[2];
    if ((n & 63) == 0) { redB[n >> 6] = sB; redC[n >> 6] = sC; }
    __syncthreads();
    float rB = sqrtf((redB[0] + redB[1]) * (1.f / 128.f) + 1e-5f);
    float rC = sqrtf((redC[0] + redC[1]) * (1.f / 128.f) + 1e-5f);
    float bn = vB / rB * Bw[n];
    float cn = vC / rC * Cw[n];
    float bp = __shfl_xor(bn, 1);
    float cp = __shfl_xor(cn, 1);
    float ob = bn, oc = cn;
    if (n < 64) {
        float c = cosb[row * NA + (n >> 1)];
        float sn_ = sinb[row * NA + (n >> 1)];
        if ((n & 1) == 0) { ob = bn * c - bp * sn_; oc = cn * c - cp * sn_; }
        else              { ob = bp * sn_ + bn * c; oc = cp * sn_ + cn * c; }
    }
    Bn[row * DS + n] = ob;
    Cn[row * DS + n] = oc;
    if (n < NH) {
        int h = n;
        float dtv = softplus_f(pr[OFF_DT + h] + dt_bias[h]);
        float Av = -fmaxf(softplus_f(pr[OFF_A + h]), 1e-4f);
        float trap = 1.f / (1.f + expf(-pr[OFF_TRAP + h]));
        size_t o = ((size_t)(b * NH + h)) * S_LEN + s;
        ldb[o]   = Av * dtv;          // log alpha
        wbuf[o]  = trap * dtv;        // immediate weight g
        pubuf[o] = (1.f - trap) * dtv; // deferred weight b/alpha
    }
}

// ---------------------------------------------------------------------------
// Inclusive cumsum of log-decay per (b,h) row, in place. 64 blocks.
// ---------------------------------------------------------------------------
__global__ __launch_bounds__(256)
void lcum_kernel(float* __restrict__ ell) {
    size_t row = blockIdx.x;
    int tid = threadIdx.x;
    float* p = ell + row * S_LEN;
    float v[8];
    float run = 0.f;
#pragma unroll
    for (int e = 0; e < 8; ++e) { v[e] = p[tid * 8 + e]; run += v[e]; }
    __shared__ float part[256];
    part[tid] = run;
    __syncthreads();
    for (int off = 1; off < 256; off <<= 1) {
        float add = (tid >= off) ? part[tid - off] : 0.f;
        __syncthreads();
        part[tid] += add;
        __syncthreads();
    }
    float acc = (tid > 0) ? part[tid - 1] : 0.f;
#pragma unroll
    for (int e = 0; e < 8; ++e) { acc += v[e]; p[tid * 8 + e] = acc; }
}

// ---------------------------------------------------------------------------
// Build K/Q matrix (base + rotated bias). Non-transposed: M[t][n], row pad 132.
// ---------------------------------------------------------------------------
__device__ __forceinline__ void build_mat(
    float (*Ms)[132], const float* __restrict__ base,
    const float* __restrict__ bias,
    const float* __restrict__ cosv, const float* __restrict__ sinv, int tid) {
    int t = tid >> 2;
    int nq = tid & 3;
    int n0 = nq * 32;
    const float* br = base + (size_t)t * DS + n0;
    if (nq < 2) {
        const float* cr = cosv + (size_t)t * NA + nq * 16;
        const float* sr = sinv + (size_t)t * NA + nq * 16;
#pragma unroll
        for (int a = 0; a < 16; ++a) {
            float c = cr[a], s = sr[a];
            float e = bias[n0 + 2 * a], o = bias[n0 + 2 * a + 1];
            Ms[t][n0 + 2 * a]     = br[2 * a]     + e * c - o * s;
            Ms[t][n0 + 2 * a + 1] = br[2 * a + 1] + e * s + o * c;
        }
    } else {
#pragma unroll
        for (int j = 0; j < 32; j += 4) {
            float4 bv = *(const float4*)(br + j);
            Ms[t][n0 + j]     = bv.x + bias[n0 + j];
            Ms[t][n0 + j + 1] = bv.y + bias[n0 + j + 1];
            Ms[t][n0 + j + 2] = bv.z + bias[n0 + j + 2];
            Ms[t][n0 + j + 3] = bv.w + bias[n0 + j + 3];
        }
    }
}

// Transposed build: MT[n][t], row pad 68.
__device__ __forceinline__ void build_mat_T(
    float (*MT)[68], const float* __restrict__ base,
    const float* __restrict__ bias,
    const float* __restrict__ cosv, const float* __restrict__ sinv, int tid) {
    int t = tid >> 2;
    int nq = tid & 3;
    int n0 = nq * 32;
    const float* br = base + (size_t)t * DS + n0;
    if (nq < 2) {
        const float* cr = cosv + (size_t)t * NA + nq * 16;
        const float* sr = sinv + (size_t)t * NA + nq * 16;
#pragma unroll
        for (int a = 0; a < 16; ++a) {
            float c = cr[a], s = sr[a];
            float e = bias[n0 + 2 * a], o = bias[n0 + 2 * a + 1];
            MT[n0 + 2 * a][t]     = br[2 * a]     + e * c - o * s;
            MT[n0 + 2 * a + 1][t] = br[2 * a + 1] + e * s + o * c;
        }
    } else {
#pragma unroll
        for (int j = 0; j < 32; j += 4) {
            float4 bv = *(const float4*)(br + j);
            MT[n0 + j][t]     = bv.x + bias[n0 + j];
            MT[n0 + j + 1][t] = bv.y + bias[n0 + j + 1];
            MT[n0 + j + 2][t] = bv.z + bias[n0 + j + 2];
            MT[n0 + j + 3][t] = bv.w + bias[n0 + j + 3];
        }
    }
}

// ---------------------------------------------------------------------------
// Per-chunk state delta: Delta[p][n] = sum_i exp(l_last - l_i)*u_i*v_i[p]*k_i[n]
// grid = NBATCH*NH*NC = 2048 blocks, 256 threads.
// ---------------------------------------------------------------------------
__global__ __launch_bounds__(256)
void delta_kernel(const float* __restrict__ proj, const float* __restrict__ Bn,
                  const float* __restrict__ cosb, const float* __restrict__ sinb,
                  const float* __restrict__ ell, const float* __restrict__ wbuf,
                  const float* __restrict__ pubuf, const float* __restrict__ B_bias,
                  float* __restrict__ delta, float* __restrict__ rbuf) {
    __shared__ float Ks[CHK][132];
    __shared__ float cVs[CHK][68];
    __shared__ float scoef[CHK];
    int blk = blockIdx.x;
    int c = blk & (NC - 1);
    int h = (blk >> 5) & (NH - 1);
    int b = blk >> 10;
    int tid = threadIdx.x;
    size_t row0 = (size_t)b * S_LEN + c * CHK;
    size_t bh = (size_t)b * NH + h;

    build_mat(Ks, Bn + row0 * DS, B_bias + h * DS, cosb + row0 * NA, sinb + row0 * NA, tid);

    if (tid < CHK) {
        int t = tid;
        size_t so = bh * S_LEN + c * CHK + t;
        float lt = ell[so];
        float llast = ell[bh * S_LEN + c * CHK + CHK - 1];
        float u = wbuf[so];
        if (c * CHK + t < S_LEN - 1) u += pubuf[so + 1];
        scoef[t] = expf(llast - lt) * u;
        if (t == 0) {
            float base = (c == 0) ? 0.f : ell[bh * S_LEN + c * CHK - 1];
            rbuf[blk] = expf(llast - base);
        }
    }
    __syncthreads();
    {
        int t = tid >> 2, p0 = (tid & 3) * 16;
        const float* vr = proj + (row0 + t) * PDIM + OFF_V + h * HD + p0;
        float cf = scoef[t];
#pragma unroll
        for (int j = 0; j < 16; j += 4) {
            float4 v = *(const float4*)(vr + j);
            cVs[t][p0 + j]     = v.x * cf;
            cVs[t][p0 + j + 1] = v.y * cf;
            cVs[t][p0 + j + 2] = v.z * cf;
            cVs[t][p0 + j + 3] = v.w * cf;
        }
    }
    __syncthreads();
    int p0 = (tid >> 4) * 4;
    int n0 = (tid & 15) * 4;
    float acc[4][8];
#pragma unroll
    for (int a = 0; a < 4; ++a)
#pragma unroll
        for (int j = 0; j < 8; ++j) acc[a][j] = 0.f;
#pragma unroll 4
    for (int i = 0; i < CHK; ++i) {
        float4 cv = *(const float4*)&cVs[i][p0];
        float4 k0 = *(const float4*)&Ks[i][n0];
        float4 k1 = *(const float4*)&Ks[i][n0 + 64];
        float cva[4] = {cv.x, cv.y, cv.z, cv.w};
        float kv[8] = {k0.x, k0.y, k0.z, k0.w, k1.x, k1.y, k1.z, k1.w};
#pragma unroll
        for (int a = 0; a < 4; ++a)
#pragma unroll
            for (int j = 0; j < 8; ++j) acc[a][j] = fmaf(cva[a], kv[j], acc[a][j]);
    }
    float* dp = delta + (bh * NC + c) * (size_t)(HD * DS);
#pragma unroll
    for (int a = 0; a < 4; ++a) {
        float4 o0 = {acc[a][0], acc[a][1], acc[a][2], acc[a][3]};
        float4 o1 = {acc[a][4], acc[a][5], acc[a][6], acc[a][7]};
        *(float4*)(dp + (p0 + a) * DS + n0) = o0;
        *(float4*)(dp + (p0 + a) * DS + n0 + 64) = o1;
    }
}

// ---------------------------------------------------------------------------
// Sequential chunk-state propagation. In place: delta slot c becomes
// state_in(c). 64 blocks (b,h), 256 threads, 32 floats each in registers.
// ---------------------------------------------------------------------------
__global__ __launch_bounds__(256)
void state_prop(float* __restrict__ delta, const float* __restrict__ rbuf) {
    size_t bh = blockIdx.x;
    int tid = threadIdx.x;
    float4 st[8];
#pragma unroll
    for (int k = 0; k < 8; ++k) st[k] = float4{0.f, 0.f, 0.f, 0.f};
    for (int c = 0; c < NC; ++c) {
        float* dp = delta + (bh * NC + c) * (size_t)(HD * DS);
        float r = rbuf[bh * NC + c];
#pragma unroll
        for (int k = 0; k < 8; ++k) {
            int off = k * 1024 + tid * 4;
            float4 d = *(const float4*)(dp + off);
            float4 s = st[k];
            *(float4*)(dp + off) = s;   // write state_in(c)
            st[k].x = fmaf(r, s.x, d.x);
            st[k].y = fmaf(r, s.y, d.y);
            st[k].z = fmaf(r, s.z, d.z);
            st[k].w = fmaf(r, s.w, d.w);
        }
    }
}

// ---------------------------------------------------------------------------
// Per-chunk output: y = (masked QK^T) V + d_t * Q state^T + D*v.
// grid = 2048 blocks, 256 threads.
// ---------------------------------------------------------------------------
__global__ __launch_bounds__(256)
void out_kernel(const float* __restrict__ proj, const float* __restrict__ Bn,
                const float* __restrict__ Cn, const float* __restrict__ cosb,
                const float* __restrict__ sinb, const float* __restrict__ ell,
                const float* __restrict__ wbuf, const float* __restrict__ pubuf,
                const float* __restrict__ B_bias, const float* __restrict__ C_bias,
                const float* __restrict__ D_param, const float* __restrict__ delta,
                float* __restrict__ y) {
    __shared__ float QT[DS][68];   // Q transposed [n][t]
    __shared__ float KT[DS][68];   // K transposed, later reused as state [n][p]
    __shared__ float Vs[CHK][68];  // V [s][p]
    __shared__ float PT[CHK][68];  // masked P transposed [s][t]
    __shared__ float s_ell[CHK], s_u[CHK], s_w[CHK], s_d[CHK];
    int blk = blockIdx.x;
    int c = blk & (NC - 1);
    int h = (blk >> 5) & (NH - 1);
    int b = blk >> 10;
    int tid = threadIdx.x;
    size_t row0 = (size_t)b * S_LEN + c * CHK;
    size_t bh = (size_t)b * NH + h;

    build_mat_T(QT, Cn + row0 * DS, C_bias + h * DS, cosb + row0 * NA, sinb + row0 * NA, tid);
    build_mat_T(KT, Bn + row0 * DS, B_bias + h * DS, cosb + row0 * NA, sinb + row0 * NA, tid);
    {
        int t = tid >> 2, p0 = (tid & 3) * 16;
        const float* vr = proj + (row0 + t) * PDIM + OFF_V + h * HD + p0;
#pragma unroll
        for (int j = 0; j < 16; j += 4) {
            float4 v = *(const float4*)(vr + j);
            *(float4*)&Vs[t][p0 + j] = v;
        }
    }
    if (tid < CHK) {
        int t = tid;
        size_t so = bh * S_LEN + c * CHK + t;
        float lt = ell[so];
        s_ell[t] = lt;
        float wv = wbuf[so];
        s_w[t] = wv;
        float u = wv;
        if (c * CHK + t < S_LEN - 1) u += pubuf[so + 1];
        s_u[t] = u;
        float base = (c == 0) ? 0.f : ell[bh * S_LEN + c * CHK - 1];
        s_d[t] = expf(lt - base);
    }
    __syncthreads();
    // P[t][s] = sum_n Q[t][n] K[s][n]
    int t0 = (tid & 15) * 4;
    int s0 = (tid >> 4) * 4;
    float pacc[4][4];
#pragma unroll
    for (int a = 0; a < 4; ++a)
#pragma unroll
        for (int bb = 0; bb < 4; ++bb) pacc[a][bb] = 0.f;
#pragma unroll 4
    for (int n = 0; n < DS; ++n) {
        float4 q4 = *(const float4*)&QT[n][t0];
        float4 k4 = *(const float4*)&KT[n][s0];
        float qa[4] = {q4.x, q4.y, q4.z, q4.w};
        float kb[4] = {k4.x, k4.y, k4.z, k4.w};
#pragma unroll
        for (int a = 0; a < 4; ++a)
#pragma unroll
            for (int bb = 0; bb < 4; ++bb) pacc[a][bb] = fmaf(qa[a], kb[bb], pacc[a][bb]);
    }
    // mask and write PT[s][t]
#pragma unroll
    for (int bb = 0; bb < 4; ++bb) {
        int s = s0 + bb;
#pragma unroll
        for (int a = 0; a < 4; ++a) {
            int t = t0 + a;
            float m;
            if (s < t)      m = expf(s_ell[t] - s_ell[s]) * s_u[s];
            else if (s == t) m = s_w[t];
            else            m = 0.f;
            PT[s][t] = pacc[a][bb] * m;
        }
    }
    __syncthreads();
    // overwrite KT with transposed state_in(c): ST[n][p]
    {
        const float* sp = delta + (bh * NC + c) * (size_t)(HD * DS);
#pragma unroll
        for (int k = 0; k < 8; ++k) {
            int e = k * 1024 + tid * 4;
            int p = e >> 7, n = e & 127;
            float4 v = *(const float4*)(sp + e);
            KT[n][p] = v.x; KT[n + 1][p] = v.y; KT[n + 2][p] = v.z; KT[n + 3][p] = v.w;
        }
    }
    __syncthreads();
    // y[t][p] = sum_s PT[s][t]*Vs[s][p] + d_t * sum_n QT[n][t]*ST[n][p] + D*v
    int tt0 = (tid & 15) * 4;
    int p0 = (tid >> 4) * 4;
    float yacc[4][4], y2[4][4];
#pragma unroll
    for (int a = 0; a < 4; ++a)
#pragma unroll
        for (int bb = 0; bb < 4; ++bb) { yacc[a][bb] = 0.f; y2[a][bb] = 0.f; }
#pragma unroll 4
    for (int s = 0; s < CHK; ++s) {
        float4 pt4 = *(const float4*)&PT[s][tt0];
        float4 v4 = *(const float4*)&Vs[s][p0];
        float pa[4] = {pt4.x, pt4.y, pt4.z, pt4.w};
        float vb[4] = {v4.x, v4.y, v4.z, v4.w};
#pragma unroll
        for (int a = 0; a < 4; ++a)
#pragma unroll
            for (int bb = 0; bb < 4; ++bb) yacc[a][bb] = fmaf(pa[a], vb[bb], yacc[a][bb]);
    }
#pragma unroll 4
    for (int n = 0; n < DS; ++n) {
        float4 q4 = *(const float4*)&QT[n][tt0];
        float4 s4 = *(const float4*)&KT[n][p0];
        float qa[4] = {q4.x, q4.y, q4.z, q4.w};
        float sb[4] = {s4.x, s4.y, s4.z, s4.w};
#pragma unroll
        for (int a = 0; a < 4; ++a)
#pragma unroll
            for (int bb = 0; bb < 4; ++bb) y2[a][bb] = fmaf(qa[a], sb[bb], y2[a][bb]);
    }
    float Dp = D_param[h];
#pragma unroll
    for (int a = 0; a < 4; ++a) {
        int t = tt0 + a;
        float dt_ = s_d[t];
        float4 o;
        o.x = yacc[a][0] + dt_ * y2[a][0] + Dp * Vs[t][p0 + 0];
        o.y = yacc[a][1] + dt_ * y2[a][1] + Dp * Vs[t][p0 + 1];
        o.z = yacc[a][2] + dt_ * y2[a][2] + Dp * Vs[t][p0 + 2];
        o.w = yacc[a][3] + dt_ * y2[a][3] + Dp * Vs[t][p0 + 3];
        *(float4*)(y + (row0 + t) * DI + h * HD + p0) = o;
    }
}

// ---------------------------------------------------------------------------
// y RMSNorm * out_norm_w * silu(z), in place.
// ---------------------------------------------------------------------------
__global__ __launch_bounds__(256)
void ynorm_kernel(float* __restrict__ y, const float* __restrict__ proj,
                  const float* __restrict__ w) {
    size_t row = blockIdx.x;
    int tid = threadIdx.x;
    float* yr = y + row * (size_t)DI;
    float4 v0 = *(const float4*)(yr + tid * 8);
    float4 v1 = *(const float4*)(yr + tid * 8 + 4);
    float ss = v0.x * v0.x + v0.y * v0.y + v0.z * v0.z + v0.w * v0.w +
               v1.x * v1.x + v1.y * v1.y + v1.z * v1.z + v1.w * v1.w;
#pragma unroll
    for (int off = 32; off >= 1; off >>= 1) ss += __shfl_xor(ss, off);
    __shared__ float red[4];
    if ((tid & 63) == 0) red[tid >> 6] = ss;
    __syncthreads();
    float tot = red[0] + red[1] + red[2] + red[3];
    float rinv = 1.f / sqrtf(tot * (1.f / 2048.f) + 1e-5f);
    const float* zr = proj + row * (size_t)PDIM + OFF_Z;
    float4 z0 = *(const float4*)(zr + tid * 8);
    float4 z1 = *(const float4*)(zr + tid * 8 + 4);
    float4 w0 = *(const float4*)(w + tid * 8);
    float4 w1 = *(const float4*)(w + tid * 8 + 4);
    float yv[8] = {v0.x, v0.y, v0.z, v0.w, v1.x, v1.y, v1.z, v1.w};
    float zv[8] = {z0.x, z0.y, z0.z, z0.w, z1.x, z1.y, z1.z, z1.w};
    float wv[8] = {w0.x, w0.y, w0.z, w0.w, w1.x, w1.y, w1.z, w1.w};
    float ov[8];
#pragma unroll
    for (int e = 0; e < 8; ++e) {
        float sil = zv[e] / (1.f + expf(-zv[e]));
        ov[e] = yv[e] * rinv * wv[e] * sil;
    }
    float4 o0 = {ov[0], ov[1], ov[2], ov[3]};
    float4 o1 = {ov[4], ov[5], ov[6], ov[7]};
    *(float4*)(yr + tid * 8) = o0;
    *(float4*)(yr + tid * 8 + 4) = o1;
}

// ---------------------------------------------------------------------------
extern "C" void kernel_launch(void* const* d_in, const int* in_sizes, int n_in,
                              void* d_out, int out_size, void* d_ws, size_t ws_size,
                              hipStream_t stream) {
    const float* x          = (const float*)d_in[0];
    const float* W_in       = (const float*)d_in[1];
    const float* dt_bias    = (const float*)d_in[2];
    const float* B_norm_w   = (const float*)d_in[3];
    const float* C_norm_w   = (const float*)d_in[4];
    const float* B_bias     = (const float*)d_in[5];
    const float* C_bias     = (const float*)d_in[6];
    const float* D_param    = (const float*)d_in[7];
    const float* out_norm_w = (const float*)d_in[8];
    const float* W_out      = (const float*)d_in[9];
    float* out = (float*)d_out;

    const size_t M = (size_t)NBATCH * S_LEN;  // 4096
    float* ws = (float*)d_ws;
    size_t off = 0;
    float* proj  = ws + off; off += M * PDIM;
    float* cosb  = ws + off; off += M * NA;
    float* sinb  = ws + off; off += M * NA;
    float* Bn    = ws + off; off += M * DS;
    float* Cn    = ws + off; off += M * DS;
    float* ell   = ws + off; off += (size_t)NBATCH * NH * S_LEN;
    float* wbuf  = ws + off; off += (size_t)NBATCH * NH * S_LEN;
    float* pubuf = ws + off; off += (size_t)NBATCH * NH * S_LEN;
    float* delta = ws + off; off += (size_t)NBATCH * NH * NC * HD * DS;  // 16.8M
    float* rbuf  = ws + off; off += (size_t)NBATCH * NH * NC;
    float* y     = ws + off; off += M * DI;

    // 1) proj = x @ W_in^T
    sgemm_nt<<<dim3((PDIM / 128) * (M / 128)), 256, 0, stream>>>(x, W_in, proj, (int)M, PDIM, DMODEL);
    // 2) phase cumsum -> cos/sin
    phase_kernel<<<dim3(NBATCH * NA), 256, 0, stream>>>(proj, cosb, sinb);
    // 3) per-row prep (Bn/Cn rotated norms + per-head scalars)
    prep_kernel<<<dim3((int)M), 128, 0, stream>>>(proj, dt_bias, B_norm_w, C_norm_w,
                                                  cosb, sinb, Bn, Cn, ell, wbuf, pubuf);
    // 4) cumsum of log-decay
    lcum_kernel<<<dim3(NBATCH * NH), 256, 0, stream>>>(ell);
    // 5) per-chunk delta states
    delta_kernel<<<dim3(NBATCH * NH * NC), 256, 0, stream>>>(proj, Bn, cosb, sinb, ell,
                                                             wbuf, pubuf, B_bias, delta, rbuf);
    // 6) chunk-state propagation (delta -> state_in, in place)
    state_prop<<<dim3(NBATCH * NH), 256, 0, stream>>>(delta, rbuf);
    // 7) per-chunk outputs
    out_kernel<<<dim3(NBATCH * NH * NC), 256, 0, stream>>>(proj, Bn, Cn, cosb, sinb, ell,
                                                           wbuf, pubuf, B_bias, C_bias,
                                                           D_param, delta, y);
    // 8) y = rmsnorm(y)*w*silu(z)
    ynorm_kernel<<<dim3((int)M), 256, 0, stream>>>(y, proj, out_norm_w);
    // 9) out = y @ W_out^T
    sgemm_nt<<<dim3((DMODEL / 128) * (M / 128)), 256, 0, stream>>>(y, W_out, out, (int)M, DMODEL, DI);
}

// Round 3
// 405.972 us; speedup vs baseline: 4.9948x; 2.5896x over previous
//
#include <hip/hip_runtime.h>
#include <math.h>

#define S_LEN 2048
#define NBATCH 2
#define DMODEL 1024
#define PDIM 4480   // 2*2048 + 2*128 + 3*32 + 32
#define DI 2048
#define NH 32
#define HD 64
#define DS 128
#define NA 32
#define CHK 64
#define NC (S_LEN / CHK)   // 32 chunks per batch
// proj column offsets
#define OFF_Z 0
#define OFF_V 2048
#define OFF_B 4096
#define OFF_C 4224
#define OFF_DT 4352
#define OFF_A 4384
#define OFF_TRAP 4416
#define OFF_ANG 4448

typedef __attribute__((ext_vector_type(8))) short s8v;
typedef __attribute__((ext_vector_type(4))) float f4v;

__device__ __forceinline__ float softplus_f(float x) {
    return x > 20.f ? x : log1pf(expf(x));
}

__device__ __forceinline__ ushort f2bf(float f) {
    unsigned u = __float_as_uint(f);
    unsigned r = (u + 0x7fffu + ((u >> 16) & 1u)) >> 16;
    return (ushort)r;
}

// ---------------------------------------------------------------------------
// fp32 -> bf16 with per-row chunk swizzle: chunk index c (16B units) within a
// row of K elems gets c ^= (row&7). shift = log2(K/8).
// ---------------------------------------------------------------------------
__global__ __launch_bounds__(256)
void f2bf_swz(const float* __restrict__ in, ushort* __restrict__ out,
              int nchunks, int shift) {
    int idx = blockIdx.x * 256 + threadIdx.x;
    if (idx >= nchunks) return;
    int dst = idx ^ ((idx >> shift) & 7);
    const float* ip = in + (size_t)idx * 8;
    float4 v0 = *(const float4*)ip;
    float4 v1 = *(const float4*)(ip + 4);
    uint4 o;
    o.x = (unsigned)f2bf(v0.x) | ((unsigned)f2bf(v0.y) << 16);
    o.y = (unsigned)f2bf(v0.z) | ((unsigned)f2bf(v0.w) << 16);
    o.z = (unsigned)f2bf(v1.x) | ((unsigned)f2bf(v1.y) << 16);
    o.w = (unsigned)f2bf(v1.z) | ((unsigned)f2bf(v1.w) << 16);
    *(uint4*)(out + (size_t)dst * 8) = o;
}

// ---------------------------------------------------------------------------
// bf16 MFMA GEMM NT: C[m][n] = sum_k A[m][k]*B[n][k]. A:[M][K] bf16 swizzled,
// B:[N][K] bf16 swizzled, C fp32. 128x128 tile, BK=64, 256 thr (4 waves 2x2).
// ---------------------------------------------------------------------------
__global__ __launch_bounds__(256, 2)
void gemm_bf16(const ushort* __restrict__ A, const ushort* __restrict__ B,
               float* __restrict__ C, int M, int N, int K) {
    __shared__ __align__(16) short lA[128 * 64];
    __shared__ __align__(16) short lB[128 * 64];
    int nwg = gridDim.x;
    int bid = blockIdx.x;
    int q = nwg >> 3;                       // grids are multiples of 8
    int swz = (bid & 7) * q + (bid >> 3);   // XCD-contiguous chunks
    int nb = N >> 7;
    int bx = swz % nb, by = swz / nb;

    int tid = threadIdx.x;
    int wv = tid >> 6, ln = tid & 63;
    int rl = ln & 15, kg = ln >> 4, r7 = rl & 7;
    int R0 = (wv >> 1) * 64, C0 = (wv & 1) * 64;

    const ushort* Ag = A + (size_t)(by * 128 + wv * 32 + (ln >> 3)) * K + (ln & 7) * 8;
    const ushort* Bg = B + (size_t)(bx * 128 + wv * 32 + (ln >> 3)) * K + (ln & 7) * 8;
    short* lAw = lA + (wv * 32) * 64;
    short* lBw = lB + (wv * 32) * 64;

    f4v acc[4][4];
#pragma unroll
    for (int m = 0; m < 4; ++m)
#pragma unroll
        for (int n = 0; n < 4; ++n) acc[m][n] = f4v{0.f, 0.f, 0.f, 0.f};

    for (int k0 = 0; k0 < K; k0 += 64) {
        __syncthreads();
#pragma unroll
        for (int i = 0; i < 4; ++i) {
            __builtin_amdgcn_global_load_lds(
                (const __attribute__((address_space(1))) void*)(Ag + (size_t)i * 8 * K + k0),
                (__attribute__((address_space(3))) void*)(lAw + i * 8 * 64), 16, 0, 0);
            __builtin_amdgcn_global_load_lds(
                (const __attribute__((address_space(1))) void*)(Bg + (size_t)i * 8 * K + k0),
                (__attribute__((address_space(3))) void*)(lBw + i * 8 * 64), 16, 0, 0);
        }
        __syncthreads();
#pragma unroll
        for (int ks = 0; ks < 2; ++ks) {
            int kc = ks * 4 + kg;
            int co = ((kc ^ r7) << 3);
            s8v av[4], bv[4];
#pragma unroll
            for (int m = 0; m < 4; ++m)
                av[m] = *(const s8v*)&lA[(R0 + m * 16 + rl) * 64 + co];
#pragma unroll
            for (int n = 0; n < 4; ++n)
                bv[n] = *(const s8v*)&lB[(C0 + n * 16 + rl) * 64 + co];
#pragma unroll
            for (int m = 0; m < 4; ++m)
#pragma unroll
                for (int n = 0; n < 4; ++n)
                    acc[m][n] = __builtin_amdgcn_mfma_f32_16x16x32_bf16(
                        av[m], bv[n], acc[m][n], 0, 0, 0);
        }
    }
#pragma unroll
    for (int m = 0; m < 4; ++m)
#pragma unroll
        for (int n = 0; n < 4; ++n) {
            size_t row0 = (size_t)(by * 128 + R0 + m * 16 + kg * 4);
            int col = bx * 128 + C0 + n * 16 + rl;
#pragma unroll
            for (int r = 0; r < 4; ++r)
                C[(row0 + r) * N + col] = acc[m][n][r];
        }
}

// ---------------------------------------------------------------------------
// Phase cumsum + cos/sin. grid = NBATCH*NA, 256 threads, 8 elems each.
// ---------------------------------------------------------------------------
__global__ __launch_bounds__(256)
void phase_kernel(const float* __restrict__ proj, float* __restrict__ cosb,
                  float* __restrict__ sinb) {
    int b = blockIdx.x >> 5;
    int j = blockIdx.x & 31;
    int tid = threadIdx.x;
    __shared__ float part[256];
    float v[8];
    float run = 0.f;
#pragma unroll
    for (int e = 0; e < 8; ++e) {
        int s = tid * 8 + e;
        v[e] = proj[((size_t)(b * S_LEN + s)) * PDIM + OFF_ANG + j];
        run += v[e];
    }
    part[tid] = run;
    __syncthreads();
    for (int off = 1; off < 256; off <<= 1) {
        float add = (tid >= off) ? part[tid - off] : 0.f;
        __syncthreads();
        part[tid] += add;
        __syncthreads();
    }
    float acc = (tid > 0) ? part[tid - 1] : 0.f;
#pragma unroll
    for (int e = 0; e < 8; ++e) {
        acc += v[e];
        int s = tid * 8 + e;
        size_t o = ((size_t)(b * S_LEN + s)) * NA + j;
        cosb[o] = cosf(acc);
        sinb[o] = sinf(acc);
    }
}

// ---------------------------------------------------------------------------
// Per-(b,s) prep: RMSNorm B/C (rotate norm part), per-head scalars.
// ---------------------------------------------------------------------------
__global__ __launch_bounds__(128)
void prep_kernel(const float* __restrict__ proj, const float* __restrict__ dt_bias,
                 const float* __restrict__ Bw, const float* __restrict__ Cw,
                 const float* __restrict__ cosb, const float* __restrict__ sinb,
                 float* __restrict__ Bn, float* __restrict__ Cn,
                 float* __restrict__ ldb, float* __restrict__ wbuf,
                 float* __restrict__ pubuf) {
    size_t row = blockIdx.x;
    int b = (int)(row >> 11);
    int s = (int)(row & 2047);
    int n = threadIdx.x;
    const float* pr = proj + row * PDIM;
    float vB = pr[OFF_B + n];
    float vC = pr[OFF_C + n];
    float sB = vB * vB, sC = vC * vC;
#pragma unroll
    for (int off = 32; off >= 1; off >>= 1) {
        sB += __shfl_xor(sB, off);
        sC += __shfl_xor(sC, off);
    }
    __shared__ float redB[2], redC[2];
    if ((n & 63) == 0) { redB[n >> 6] = sB; redC[n >> 6] = sC; }
    __syncthreads();
    float rB = sqrtf((redB[0] + redB[1]) * (1.f / 128.f) + 1e-5f);
    float rC = sqrtf((redC[0] + redC[1]) * (1.f / 128.f) + 1e-5f);
    float bn = vB / rB * Bw[n];
    float cn = vC / rC * Cw[n];
    float bp = __shfl_xor(bn, 1);
    float cp = __shfl_xor(cn, 1);
    float ob = bn, oc = cn;
    if (n < 64) {
        float c = cosb[row * NA + (n >> 1)];
        float sn_ = sinb[row * NA + (n >> 1)];
        if ((n & 1) == 0) { ob = bn * c - bp * sn_; oc = cn * c - cp * sn_; }
        else              { ob = bp * sn_ + bn * c; oc = cp * sn_ + cn * c; }
    }
    Bn[row * DS + n] = ob;
    Cn[row * DS + n] = oc;
    if (n < NH) {
        int h = n;
        float dtv = softplus_f(pr[OFF_DT + h] + dt_bias[h]);
        float Av = -fmaxf(softplus_f(pr[OFF_A + h]), 1e-4f);
        float trap = 1.f / (1.f + expf(-pr[OFF_TRAP + h]));
        size_t o = ((size_t)(b * NH + h)) * S_LEN + s;
        ldb[o]   = Av * dtv;
        wbuf[o]  = trap * dtv;
        pubuf[o] = (1.f - trap) * dtv;
    }
}

// ---------------------------------------------------------------------------
// Inclusive cumsum of log-decay per (b,h) row, in place. 64 blocks.
// ---------------------------------------------------------------------------
__global__ __launch_bounds__(256)
void lcum_kernel(float* __restrict__ ell) {
    size_t row = blockIdx.x;
    int tid = threadIdx.x;
    float* p = ell + row * S_LEN;
    float v[8];
    float run = 0.f;
#pragma unroll
    for (int e = 0; e < 8; ++e) { v[e] = p[tid * 8 + e]; run += v[e]; }
    __shared__ float part[256];
    part[tid] = run;
    __syncthreads();
    for (int off = 1; off < 256; off <<= 1) {
        float add = (tid >= off) ? part[tid - off] : 0.f;
        __syncthreads();
        part[tid] += add;
        __syncthreads();
    }
    float acc = (tid > 0) ? part[tid - 1] : 0.f;
#pragma unroll
    for (int e = 0; e < 8; ++e) { acc += v[e]; p[tid * 8 + e] = acc; }
}

// ---------------------------------------------------------------------------
// Build K/Q matrix (base + rotated bias). Non-transposed: M[t][n], row pad 132.
// ---------------------------------------------------------------------------
__device__ __forceinline__ void build_mat(
    float (*Ms)[132], const float* __restrict__ base,
    const float* __restrict__ bias,
    const float* __restrict__ cosv, const float* __restrict__ sinv, int tid) {
    int t = tid >> 2;
    int nq = tid & 3;
    int n0 = nq * 32;
    const float* br = base + (size_t)t * DS + n0;
    if (nq < 2) {
        const float* cr = cosv + (size_t)t * NA + nq * 16;
        const float* sr = sinv + (size_t)t * NA + nq * 16;
#pragma unroll
        for (int a = 0; a < 16; ++a) {
            float c = cr[a], s = sr[a];
            float e = bias[n0 + 2 * a], o = bias[n0 + 2 * a + 1];
            Ms[t][n0 + 2 * a]     = br[2 * a]     + e * c - o * s;
            Ms[t][n0 + 2 * a + 1] = br[2 * a + 1] + e * s + o * c;
        }
    } else {
#pragma unroll
        for (int j = 0; j < 32; j += 4) {
            float4 bv = *(const float4*)(br + j);
            Ms[t][n0 + j]     = bv.x + bias[n0 + j];
            Ms[t][n0 + j + 1] = bv.y + bias[n0 + j + 1];
            Ms[t][n0 + j + 2] = bv.z + bias[n0 + j + 2];
            Ms[t][n0 + j + 3] = bv.w + bias[n0 + j + 3];
        }
    }
}

// Transposed build: MT[n][t], row pad 68.
__device__ __forceinline__ void build_mat_T(
    float (*MT)[68], const float* __restrict__ base,
    const float* __restrict__ bias,
    const float* __restrict__ cosv, const float* __restrict__ sinv, int tid) {
    int t = tid >> 2;
    int nq = tid & 3;
    int n0 = nq * 32;
    const float* br = base + (size_t)t * DS + n0;
    if (nq < 2) {
        const float* cr = cosv + (size_t)t * NA + nq * 16;
        const float* sr = sinv + (size_t)t * NA + nq * 16;
#pragma unroll
        for (int a = 0; a < 16; ++a) {
            float c = cr[a], s = sr[a];
            float e = bias[n0 + 2 * a], o = bias[n0 + 2 * a + 1];
            MT[n0 + 2 * a][t]     = br[2 * a]     + e * c - o * s;
            MT[n0 + 2 * a + 1][t] = br[2 * a + 1] + e * s + o * c;
        }
    } else {
#pragma unroll
        for (int j = 0; j < 32; j += 4) {
            float4 bv = *(const float4*)(br + j);
            MT[n0 + j][t]     = bv.x + bias[n0 + j];
            MT[n0 + j + 1][t] = bv.y + bias[n0 + j + 1];
            MT[n0 + j + 2][t] = bv.z + bias[n0 + j + 2];
            MT[n0 + j + 3][t] = bv.w + bias[n0 + j + 3];
        }
    }
}

// ---------------------------------------------------------------------------
// Per-chunk state delta.
// ---------------------------------------------------------------------------
__global__ __launch_bounds__(256)
void delta_kernel(const float* __restrict__ proj, const float* __restrict__ Bn,
                  const float* __restrict__ cosb, const float* __restrict__ sinb,
                  const float* __restrict__ ell, const float* __restrict__ wbuf,
                  const float* __restrict__ pubuf, const float* __restrict__ B_bias,
                  float* __restrict__ delta, float* __restrict__ rbuf) {
    __shared__ float Ks[CHK][132];
    __shared__ float cVs[CHK][68];
    __shared__ float scoef[CHK];
    int blk = blockIdx.x;
    int c = blk & (NC - 1);
    int h = (blk >> 5) & (NH - 1);
    int b = blk >> 10;
    int tid = threadIdx.x;
    size_t row0 = (size_t)b * S_LEN + c * CHK;
    size_t bh = (size_t)b * NH + h;

    build_mat(Ks, Bn + row0 * DS, B_bias + h * DS, cosb + row0 * NA, sinb + row0 * NA, tid);

    if (tid < CHK) {
        int t = tid;
        size_t so = bh * S_LEN + c * CHK + t;
        float lt = ell[so];
        float llast = ell[bh * S_LEN + c * CHK + CHK - 1];
        float u = wbuf[so];
        if (c * CHK + t < S_LEN - 1) u += pubuf[so + 1];
        scoef[t] = expf(llast - lt) * u;
        if (t == 0) {
            float base = (c == 0) ? 0.f : ell[bh * S_LEN + c * CHK - 1];
            rbuf[blk] = expf(llast - base);
        }
    }
    __syncthreads();
    {
        int t = tid >> 2, p0 = (tid & 3) * 16;
        const float* vr = proj + (row0 + t) * PDIM + OFF_V + h * HD + p0;
        float cf = scoef[t];
#pragma unroll
        for (int j = 0; j < 16; j += 4) {
            float4 v = *(const float4*)(vr + j);
            cVs[t][p0 + j]     = v.x * cf;
            cVs[t][p0 + j + 1] = v.y * cf;
            cVs[t][p0 + j + 2] = v.z * cf;
            cVs[t][p0 + j + 3] = v.w * cf;
        }
    }
    __syncthreads();
    int p0 = (tid >> 4) * 4;
    int n0 = (tid & 15) * 4;
    float acc[4][8];
#pragma unroll
    for (int a = 0; a < 4; ++a)
#pragma unroll
        for (int j = 0; j < 8; ++j) acc[a][j] = 0.f;
#pragma unroll 4
    for (int i = 0; i < CHK; ++i) {
        float4 cv = *(const float4*)&cVs[i][p0];
        float4 k0 = *(const float4*)&Ks[i][n0];
        float4 k1 = *(const float4*)&Ks[i][n0 + 64];
        float cva[4] = {cv.x, cv.y, cv.z, cv.w};
        float kv[8] = {k0.x, k0.y, k0.z, k0.w, k1.x, k1.y, k1.z, k1.w};
#pragma unroll
        for (int a = 0; a < 4; ++a)
#pragma unroll
            for (int j = 0; j < 8; ++j) acc[a][j] = fmaf(cva[a], kv[j], acc[a][j]);
    }
    float* dp = delta + (bh * NC + c) * (size_t)(HD * DS);
#pragma unroll
    for (int a = 0; a < 4; ++a) {
        float4 o0 = {acc[a][0], acc[a][1], acc[a][2], acc[a][3]};
        float4 o1 = {acc[a][4], acc[a][5], acc[a][6], acc[a][7]};
        *(float4*)(dp + (p0 + a) * DS + n0) = o0;
        *(float4*)(dp + (p0 + a) * DS + n0 + 64) = o1;
    }
}

// ---------------------------------------------------------------------------
// Sequential chunk-state propagation.
// ---------------------------------------------------------------------------
__global__ __launch_bounds__(256)
void state_prop(float* __restrict__ delta, const float* __restrict__ rbuf) {
    size_t bh = blockIdx.x;
    int tid = threadIdx.x;
    float4 st[8];
#pragma unroll
    for (int k = 0; k < 8; ++k) st[k] = float4{0.f, 0.f, 0.f, 0.f};
    for (int c = 0; c < NC; ++c) {
        float* dp = delta + (bh * NC + c) * (size_t)(HD * DS);
        float r = rbuf[bh * NC + c];
#pragma unroll
        for (int k = 0; k < 8; ++k) {
            int off = k * 1024 + tid * 4;
            float4 d = *(const float4*)(dp + off);
            float4 s = st[k];
            *(float4*)(dp + off) = s;
            st[k].x = fmaf(r, s.x, d.x);
            st[k].y = fmaf(r, s.y, d.y);
            st[k].z = fmaf(r, s.z, d.z);
            st[k].w = fmaf(r, s.w, d.w);
        }
    }
}

// ---------------------------------------------------------------------------
// Per-chunk output: y = (masked QK^T) V + d_t * Q state^T + D*v.
// ---------------------------------------------------------------------------
__global__ __launch_bounds__(256)
void out_kernel(const float* __restrict__ proj, const float* __restrict__ Bn,
                const float* __restrict__ Cn, const float* __restrict__ cosb,
                const float* __restrict__ sinb, const float* __restrict__ ell,
                const float* __restrict__ wbuf, const float* __restrict__ pubuf,
                const float* __restrict__ B_bias, const float* __restrict__ C_bias,
                const float* __restrict__ D_param, const float* __restrict__ delta,
                float* __restrict__ y) {
    __shared__ float QT[DS][68];
    __shared__ float KT[DS][68];
    __shared__ float Vs[CHK][68];
    __shared__ float PT[CHK][68];
    __shared__ float s_ell[CHK], s_u[CHK], s_w[CHK], s_d[CHK];
    int blk = blockIdx.x;
    int c = blk & (NC - 1);
    int h = (blk >> 5) & (NH - 1);
    int b = blk >> 10;
    int tid = threadIdx.x;
    size_t row0 = (size_t)b * S_LEN + c * CHK;
    size_t bh = (size_t)b * NH + h;

    build_mat_T(QT, Cn + row0 * DS, C_bias + h * DS, cosb + row0 * NA, sinb + row0 * NA, tid);
    build_mat_T(KT, Bn + row0 * DS, B_bias + h * DS, cosb + row0 * NA, sinb + row0 * NA, tid);
    {
        int t = tid >> 2, p0 = (tid & 3) * 16;
        const float* vr = proj + (row0 + t) * PDIM + OFF_V + h * HD + p0;
#pragma unroll
        for (int j = 0; j < 16; j += 4) {
            float4 v = *(const float4*)(vr + j);
            *(float4*)&Vs[t][p0 + j] = v;
        }
    }
    if (tid < CHK) {
        int t = tid;
        size_t so = bh * S_LEN + c * CHK + t;
        float lt = ell[so];
        s_ell[t] = lt;
        float wv = wbuf[so];
        s_w[t] = wv;
        float u = wv;
        if (c * CHK + t < S_LEN - 1) u += pubuf[so + 1];
        s_u[t] = u;
        float base = (c == 0) ? 0.f : ell[bh * S_LEN + c * CHK - 1];
        s_d[t] = expf(lt - base);
    }
    __syncthreads();
    int t0 = (tid & 15) * 4;
    int s0 = (tid >> 4) * 4;
    float pacc[4][4];
#pragma unroll
    for (int a = 0; a < 4; ++a)
#pragma unroll
        for (int bb = 0; bb < 4; ++bb) pacc[a][bb] = 0.f;
#pragma unroll 4
    for (int n = 0; n < DS; ++n) {
        float4 q4 = *(const float4*)&QT[n][t0];
        float4 k4 = *(const float4*)&KT[n][s0];
        float qa[4] = {q4.x, q4.y, q4.z, q4.w};
        float kb[4] = {k4.x, k4.y, k4.z, k4.w};
#pragma unroll
        for (int a = 0; a < 4; ++a)
#pragma unroll
            for (int bb = 0; bb < 4; ++bb) pacc[a][bb] = fmaf(qa[a], kb[bb], pacc[a][bb]);
    }
#pragma unroll
    for (int bb = 0; bb < 4; ++bb) {
        int s = s0 + bb;
#pragma unroll
        for (int a = 0; a < 4; ++a) {
            int t = t0 + a;
            float m;
            if (s < t)      m = expf(s_ell[t] - s_ell[s]) * s_u[s];
            else if (s == t) m = s_w[t];
            else            m = 0.f;
            PT[s][t] = pacc[a][bb] * m;
        }
    }
    __syncthreads();
    {
        const float* sp = delta + (bh * NC + c) * (size_t)(HD * DS);
#pragma unroll
        for (int k = 0; k < 8; ++k) {
            int e = k * 1024 + tid * 4;
            int p = e >> 7, n = e & 127;
            float4 v = *(const float4*)(sp + e);
            KT[n][p] = v.x; KT[n + 1][p] = v.y; KT[n + 2][p] = v.z; KT[n + 3][p] = v.w;
        }
    }
    __syncthreads();
    int tt0 = (tid & 15) * 4;
    int p0 = (tid >> 4) * 4;
    float yacc[4][4], y2[4][4];
#pragma unroll
    for (int a = 0; a < 4; ++a)
#pragma unroll
        for (int bb = 0; bb < 4; ++bb) { yacc[a][bb] = 0.f; y2[a][bb] = 0.f; }
#pragma unroll 4
    for (int s = 0; s < CHK; ++s) {
        float4 pt4 = *(const float4*)&PT[s][tt0];
        float4 v4 = *(const float4*)&Vs[s][p0];
        float pa[4] = {pt4.x, pt4.y, pt4.z, pt4.w};
        float vb[4] = {v4.x, v4.y, v4.z, v4.w};
#pragma unroll
        for (int a = 0; a < 4; ++a)
#pragma unroll
            for (int bb = 0; bb < 4; ++bb) yacc[a][bb] = fmaf(pa[a], vb[bb], yacc[a][bb]);
    }
#pragma unroll 4
    for (int n = 0; n < DS; ++n) {
        float4 q4 = *(const float4*)&QT[n][tt0];
        float4 s4 = *(const float4*)&KT[n][p0];
        float qa[4] = {q4.x, q4.y, q4.z, q4.w};
        float sb[4] = {s4.x, s4.y, s4.z, s4.w};
#pragma unroll
        for (int a = 0; a < 4; ++a)
#pragma unroll
            for (int bb = 0; bb < 4; ++bb) y2[a][bb] = fmaf(qa[a], sb[bb], y2[a][bb]);
    }
    float Dp = D_param[h];
#pragma unroll
    for (int a = 0; a < 4; ++a) {
        int t = tt0 + a;
        float dt_ = s_d[t];
        float4 o;
        o.x = yacc[a][0] + dt_ * y2[a][0] + Dp * Vs[t][p0 + 0];
        o.y = yacc[a][1] + dt_ * y2[a][1] + Dp * Vs[t][p0 + 1];
        o.z = yacc[a][2] + dt_ * y2[a][2] + Dp * Vs[t][p0 + 2];
        o.w = yacc[a][3] + dt_ * y2[a][3] + Dp * Vs[t][p0 + 3];
        *(float4*)(y + (row0 + t) * DI + h * HD + p0) = o;
    }
}

// ---------------------------------------------------------------------------
// y RMSNorm * out_norm_w * silu(z) -> bf16 swizzled (GEMM2 A operand).
// ---------------------------------------------------------------------------
__global__ __launch_bounds__(256)
void ynorm_kernel(const float* __restrict__ y, const float* __restrict__ proj,
                  const float* __restrict__ w, ushort* __restrict__ ybf) {
    size_t row = blockIdx.x;
    int tid = threadIdx.x;
    const float* yr = y + row * (size_t)DI;
    float4 v0 = *(const float4*)(yr + tid * 8);
    float4 v1 = *(const float4*)(yr + tid * 8 + 4);
    float ss = v0.x * v0.x + v0.y * v0.y + v0.z * v0.z + v0.w * v0.w +
               v1.x * v1.x + v1.y * v1.y + v1.z * v1.z + v1.w * v1.w;
#pragma unroll
    for (int off = 32; off >= 1; off >>= 1) ss += __shfl_xor(ss, off);
    __shared__ float red[4];
    if ((tid & 63) == 0) red[tid >> 6] = ss;
    __syncthreads();
    float tot = red[0] + red[1] + red[2] + red[3];
    float rinv = 1.f / sqrtf(tot * (1.f / 2048.f) + 1e-5f);
    const float* zr = proj + row * (size_t)PDIM + OFF_Z;
    float4 z0 = *(const float4*)(zr + tid * 8);
    float4 z1 = *(const float4*)(zr + tid * 8 + 4);
    float4 w0 = *(const float4*)(w + tid * 8);
    float4 w1 = *(const float4*)(w + tid * 8 + 4);
    float yv[8] = {v0.x, v0.y, v0.z, v0.w, v1.x, v1.y, v1.z, v1.w};
    float zv[8] = {z0.x, z0.y, z0.z, z0.w, z1.x, z1.y, z1.z, z1.w};
    float wv[8] = {w0.x, w0.y, w0.z, w0.w, w1.x, w1.y, w1.z, w1.w};
    ushort u[8];
#pragma unroll
    for (int e = 0; e < 8; ++e) {
        float sil = zv[e] / (1.f + expf(-zv[e]));
        u[e] = f2bf(yv[e] * rinv * wv[e] * sil);
    }
    int dstc = (tid & ~7) | ((tid & 7) ^ ((int)row & 7));
    uint4 o;
    o.x = (unsigned)u[0] | ((unsigned)u[1] << 16);
    o.y = (unsigned)u[2] | ((unsigned)u[3] << 16);
    o.z = (unsigned)u[4] | ((unsigned)u[5] << 16);
    o.w = (unsigned)u[6] | ((unsigned)u[7] << 16);
    *(uint4*)(ybf + row * (size_t)DI + dstc * 8) = o;
}

// ---------------------------------------------------------------------------
extern "C" void kernel_launch(void* const* d_in, const int* in_sizes, int n_in,
                              void* d_out, int out_size, void* d_ws, size_t ws_size,
                              hipStream_t stream) {
    const float* x          = (const float*)d_in[0];
    const float* W_in       = (const float*)d_in[1];
    const float* dt_bias    = (const float*)d_in[2];
    const float* B_norm_w   = (const float*)d_in[3];
    const float* C_norm_w   = (const float*)d_in[4];
    const float* B_bias     = (const float*)d_in[5];
    const float* C_bias     = (const float*)d_in[6];
    const float* D_param    = (const float*)d_in[7];
    const float* out_norm_w = (const float*)d_in[8];
    const float* W_out      = (const float*)d_in[9];
    float* out = (float*)d_out;

    const size_t M = (size_t)NBATCH * S_LEN;  // 4096
    float* ws = (float*)d_ws;
    size_t off = 0;
    float* proj  = ws + off; off += M * PDIM;
    float* cosb  = ws + off; off += M * NA;
    float* sinb  = ws + off; off += M * NA;
    float* Bn    = ws + off; off += M * DS;
    float* Cn    = ws + off; off += M * DS;
    float* ell   = ws + off; off += (size_t)NBATCH * NH * S_LEN;
    float* wbuf  = ws + off; off += (size_t)NBATCH * NH * S_LEN;
    float* pubuf = ws + off; off += (size_t)NBATCH * NH * S_LEN;
    float* delta = ws + off; off += (size_t)NBATCH * NH * NC * HD * DS;
    float* rbuf  = ws + off; off += (size_t)NBATCH * NH * NC;
    float* y     = ws + off; off += M * DI;
    ushort* xbf  = (ushort*)(ws + off); off += M * DMODEL / 2;
    ushort* wibf = (ushort*)(ws + off); off += (size_t)PDIM * DMODEL / 2;
    ushort* wobf = (ushort*)(ws + off); off += (size_t)DMODEL * DI / 2;
    ushort* ybf  = (ushort*)(ws + off); off += M * DI / 2;

    // 0) fp32 -> bf16 (swizzled) conversions
    {
        int nc_x  = (int)(M * DMODEL / 8);
        int nc_wi = PDIM * DMODEL / 8;
        int nc_wo = DMODEL * DI / 8;
        f2bf_swz<<<dim3((nc_x + 255) / 256), 256, 0, stream>>>(x, xbf, nc_x, 7);
        f2bf_swz<<<dim3((nc_wi + 255) / 256), 256, 0, stream>>>(W_in, wibf, nc_wi, 7);
        f2bf_swz<<<dim3((nc_wo + 255) / 256), 256, 0, stream>>>(W_out, wobf, nc_wo, 8);
    }
    // 1) proj = x @ W_in^T  (bf16 MFMA)
    gemm_bf16<<<dim3((PDIM / 128) * (int)(M / 128)), 256, 0, stream>>>(xbf, wibf, proj, (int)M, PDIM, DMODEL);
    // 2) phase cumsum -> cos/sin
    phase_kernel<<<dim3(NBATCH * NA), 256, 0, stream>>>(proj, cosb, sinb);
    // 3) per-row prep
    prep_kernel<<<dim3((int)M), 128, 0, stream>>>(proj, dt_bias, B_norm_w, C_norm_w,
                                                  cosb, sinb, Bn, Cn, ell, wbuf, pubuf);
    // 4) cumsum of log-decay
    lcum_kernel<<<dim3(NBATCH * NH), 256, 0, stream>>>(ell);
    // 5) per-chunk delta states
    delta_kernel<<<dim3(NBATCH * NH * NC), 256, 0, stream>>>(proj, Bn, cosb, sinb, ell,
                                                             wbuf, pubuf, B_bias, delta, rbuf);
    // 6) chunk-state propagation
    state_prop<<<dim3(NBATCH * NH), 256, 0, stream>>>(delta, rbuf);
    // 7) per-chunk outputs
    out_kernel<<<dim3(NBATCH * NH * NC), 256, 0, stream>>>(proj, Bn, Cn, cosb, sinb, ell,
                                                           wbuf, pubuf, B_bias, C_bias,
                                                           D_param, delta, y);
    // 8) y = rmsnorm(y)*w*silu(z) -> bf16 swizzled
    ynorm_kernel<<<dim3((int)M), 256, 0, stream>>>(y, proj, out_norm_w, ybf);
    // 9) out = y @ W_out^T  (bf16 MFMA)
    gemm_bf16<<<dim3((DMODEL / 128) * (int)(M / 128)), 256, 0, stream>>>(ybf, wobf, out, (int)M, DMODEL, DI);
}

// Round 4
// 266.974 us; speedup vs baseline: 7.5953x; 1.5206x over previous
//
#include <hip/hip_runtime.h>
#include <math.h>

#define S_LEN 2048
#define NBATCH 2
#define DMODEL 1024
#define PDIM 4480   // 2*2048 + 2*128 + 3*32 + 32
#define DI 2048
#define NH 32
#define HD 64
#define DS 128
#define NA 32
#define CHK 64
#define NC (S_LEN / CHK)   // 32 chunks per batch
// proj column offsets
#define OFF_Z 0
#define OFF_V 2048
#define OFF_B 4096
#define OFF_C 4224
#define OFF_DT 4352
#define OFF_A 4384
#define OFF_TRAP 4416
#define OFF_ANG 4448

typedef __attribute__((ext_vector_type(8))) short s8v;
typedef __attribute__((ext_vector_type(4))) float f4v;

__device__ __forceinline__ float softplus_f(float x) {
    return x > 20.f ? x : log1pf(expf(x));
}

__device__ __forceinline__ ushort f2bf(float f) {
    unsigned u = __float_as_uint(f);
    unsigned r = (u + 0x7fffu + ((u >> 16) & 1u)) >> 16;
    return (ushort)r;
}

__device__ __forceinline__ uint4 pack8(const float* f) {
    uint4 o;
    o.x = (unsigned)f2bf(f[0]) | ((unsigned)f2bf(f[1]) << 16);
    o.y = (unsigned)f2bf(f[2]) | ((unsigned)f2bf(f[3]) << 16);
    o.z = (unsigned)f2bf(f[4]) | ((unsigned)f2bf(f[5]) << 16);
    o.w = (unsigned)f2bf(f[6]) | ((unsigned)f2bf(f[7]) << 16);
    return o;
}

__device__ __forceinline__ float bf2f(ushort u) {
    unsigned v = ((unsigned)u) << 16;
    return __uint_as_float(v);
}

// ---------------------------------------------------------------------------
// fp32 -> bf16 with per-row chunk swizzle (16B chunks, c ^= row&7).
// ---------------------------------------------------------------------------
__global__ __launch_bounds__(256)
void f2bf_swz(const float* __restrict__ in, ushort* __restrict__ out,
              int nchunks, int shift) {
    int idx = blockIdx.x * 256 + threadIdx.x;
    if (idx >= nchunks) return;
    int dst = idx ^ ((idx >> shift) & 7);
    const float* ip = in + (size_t)idx * 8;
    float4 v0 = *(const float4*)ip;
    float4 v1 = *(const float4*)(ip + 4);
    uint4 o;
    o.x = (unsigned)f2bf(v0.x) | ((unsigned)f2bf(v0.y) << 16);
    o.y = (unsigned)f2bf(v0.z) | ((unsigned)f2bf(v0.w) << 16);
    o.z = (unsigned)f2bf(v1.x) | ((unsigned)f2bf(v1.y) << 16);
    o.w = (unsigned)f2bf(v1.z) | ((unsigned)f2bf(v1.w) << 16);
    *(uint4*)(out + (size_t)dst * 8) = o;
}

// ---------------------------------------------------------------------------
// bf16 MFMA GEMM NT (A,B pre-swizzled). 128x128 tile, BK=64, 4 waves 2x2.
// ---------------------------------------------------------------------------
__global__ __launch_bounds__(256, 2)
void gemm_bf16(const ushort* __restrict__ A, const ushort* __restrict__ B,
               float* __restrict__ C, int M, int N, int K) {
    __shared__ __align__(16) short lA[128 * 64];
    __shared__ __align__(16) short lB[128 * 64];
    int nwg = gridDim.x;
    int bid = blockIdx.x;
    int q = nwg >> 3;
    int swz = (bid & 7) * q + (bid >> 3);
    int nb = N >> 7;
    int bx = swz % nb, by = swz / nb;

    int tid = threadIdx.x;
    int wv = tid >> 6, ln = tid & 63;
    int rl = ln & 15, kg = ln >> 4, r7 = rl & 7;
    int R0 = (wv >> 1) * 64, C0 = (wv & 1) * 64;

    const ushort* Ag = A + (size_t)(by * 128 + wv * 32 + (ln >> 3)) * K + (ln & 7) * 8;
    const ushort* Bg = B + (size_t)(bx * 128 + wv * 32 + (ln >> 3)) * K + (ln & 7) * 8;
    short* lAw = lA + (wv * 32) * 64;
    short* lBw = lB + (wv * 32) * 64;

    f4v acc[4][4];
#pragma unroll
    for (int m = 0; m < 4; ++m)
#pragma unroll
        for (int n = 0; n < 4; ++n) acc[m][n] = f4v{0.f, 0.f, 0.f, 0.f};

    for (int k0 = 0; k0 < K; k0 += 64) {
        __syncthreads();
#pragma unroll
        for (int i = 0; i < 4; ++i) {
            __builtin_amdgcn_global_load_lds(
                (const __attribute__((address_space(1))) void*)(Ag + (size_t)i * 8 * K + k0),
                (__attribute__((address_space(3))) void*)(lAw + i * 8 * 64), 16, 0, 0);
            __builtin_amdgcn_global_load_lds(
                (const __attribute__((address_space(1))) void*)(Bg + (size_t)i * 8 * K + k0),
                (__attribute__((address_space(3))) void*)(lBw + i * 8 * 64), 16, 0, 0);
        }
        __syncthreads();
#pragma unroll
        for (int ks = 0; ks < 2; ++ks) {
            int kc = ks * 4 + kg;
            int co = ((kc ^ r7) << 3);
            s8v av[4], bv[4];
#pragma unroll
            for (int m = 0; m < 4; ++m)
                av[m] = *(const s8v*)&lA[(R0 + m * 16 + rl) * 64 + co];
#pragma unroll
            for (int n = 0; n < 4; ++n)
                bv[n] = *(const s8v*)&lB[(C0 + n * 16 + rl) * 64 + co];
#pragma unroll
            for (int m = 0; m < 4; ++m)
#pragma unroll
                for (int n = 0; n < 4; ++n)
                    acc[m][n] = __builtin_amdgcn_mfma_f32_16x16x32_bf16(
                        av[m], bv[n], acc[m][n], 0, 0, 0);
        }
    }
#pragma unroll
    for (int m = 0; m < 4; ++m)
#pragma unroll
        for (int n = 0; n < 4; ++n) {
            size_t row0 = (size_t)(by * 128 + R0 + m * 16 + kg * 4);
            int col = bx * 128 + C0 + n * 16 + rl;
#pragma unroll
            for (int r = 0; r < 4; ++r)
                C[(row0 + r) * N + col] = acc[m][n][r];
        }
}

// ---------------------------------------------------------------------------
// Phase cumsum + cos/sin.
// ---------------------------------------------------------------------------
__global__ __launch_bounds__(256)
void phase_kernel(const float* __restrict__ proj, float* __restrict__ cosb,
                  float* __restrict__ sinb) {
    int b = blockIdx.x >> 5;
    int j = blockIdx.x & 31;
    int tid = threadIdx.x;
    __shared__ float part[256];
    float v[8];
    float run = 0.f;
#pragma unroll
    for (int e = 0; e < 8; ++e) {
        int s = tid * 8 + e;
        v[e] = proj[((size_t)(b * S_LEN + s)) * PDIM + OFF_ANG + j];
        run += v[e];
    }
    part[tid] = run;
    __syncthreads();
    for (int off = 1; off < 256; off <<= 1) {
        float add = (tid >= off) ? part[tid - off] : 0.f;
        __syncthreads();
        part[tid] += add;
        __syncthreads();
    }
    float acc = (tid > 0) ? part[tid - 1] : 0.f;
#pragma unroll
    for (int e = 0; e < 8; ++e) {
        acc += v[e];
        int s = tid * 8 + e;
        size_t o = ((size_t)(b * S_LEN + s)) * NA + j;
        cosb[o] = cosf(acc);
        sinb[o] = sinf(acc);
    }
}

// ---------------------------------------------------------------------------
// Per-(b,s) prep.
// ---------------------------------------------------------------------------
__global__ __launch_bounds__(128)
void prep_kernel(const float* __restrict__ proj, const float* __restrict__ dt_bias,
                 const float* __restrict__ Bw, const float* __restrict__ Cw,
                 const float* __restrict__ cosb, const float* __restrict__ sinb,
                 float* __restrict__ Bn, float* __restrict__ Cn,
                 float* __restrict__ ldb, float* __restrict__ wbuf,
                 float* __restrict__ pubuf) {
    size_t row = blockIdx.x;
    int b = (int)(row >> 11);
    int s = (int)(row & 2047);
    int n = threadIdx.x;
    const float* pr = proj + row * PDIM;
    float vB = pr[OFF_B + n];
    float vC = pr[OFF_C + n];
    float sB = vB * vB, sC = vC * vC;
#pragma unroll
    for (int off = 32; off >= 1; off >>= 1) {
        sB += __shfl_xor(sB, off);
        sC += __shfl_xor(sC, off);
    }
    __shared__ float redB[2], redC[2];
    if ((n & 63) == 0) { redB[n >> 6] = sB; redC[n >> 6] = sC; }
    __syncthreads();
    float rB = sqrtf((redB[0] + redB[1]) * (1.f / 128.f) + 1e-5f);
    float rC = sqrtf((redC[0] + redC[1]) * (1.f / 128.f) + 1e-5f);
    float bn = vB / rB * Bw[n];
    float cn = vC / rC * Cw[n];
    float bp = __shfl_xor(bn, 1);
    float cp = __shfl_xor(cn, 1);
    float ob = bn, oc = cn;
    if (n < 64) {
        float c = cosb[row * NA + (n >> 1)];
        float sn_ = sinb[row * NA + (n >> 1)];
        if ((n & 1) == 0) { ob = bn * c - bp * sn_; oc = cn * c - cp * sn_; }
        else              { ob = bp * sn_ + bn * c; oc = cp * sn_ + cn * c; }
    }
    Bn[row * DS + n] = ob;
    Cn[row * DS + n] = oc;
    if (n < NH) {
        int h = n;
        float dtv = softplus_f(pr[OFF_DT + h] + dt_bias[h]);
        float Av = -fmaxf(softplus_f(pr[OFF_A + h]), 1e-4f);
        float trap = 1.f / (1.f + expf(-pr[OFF_TRAP + h]));
        size_t o = ((size_t)(b * NH + h)) * S_LEN + s;
        ldb[o]   = Av * dtv;
        wbuf[o]  = trap * dtv;
        pubuf[o] = (1.f - trap) * dtv;
    }
}

// ---------------------------------------------------------------------------
// Inclusive cumsum of log-decay per (b,h) row.
// ---------------------------------------------------------------------------
__global__ __launch_bounds__(256)
void lcum_kernel(float* __restrict__ ell) {
    size_t row = blockIdx.x;
    int tid = threadIdx.x;
    float* p = ell + row * S_LEN;
    float v[8];
    float run = 0.f;
#pragma unroll
    for (int e = 0; e < 8; ++e) { v[e] = p[tid * 8 + e]; run += v[e]; }
    __shared__ float part[256];
    part[tid] = run;
    __syncthreads();
    for (int off = 1; off < 256; off <<= 1) {
        float add = (tid >= off) ? part[tid - off] : 0.f;
        __syncthreads();
        part[tid] += add;
        __syncthreads();
    }
    float acc = (tid > 0) ? part[tid - 1] : 0.f;
#pragma unroll
    for (int e = 0; e < 8; ++e) { acc += v[e]; p[tid * 8 + e] = acc; }
}

// ---------------------------------------------------------------------------
// Build 32 rotated values for row i (quarter q4) of base+bias.
// ---------------------------------------------------------------------------
__device__ __forceinline__ void build_vals32(
    float* vals, const float* __restrict__ br, const float* __restrict__ bias,
    const float* __restrict__ cr, const float* __restrict__ sr, int n0, int rot) {
    if (rot) {
#pragma unroll
        for (int a = 0; a < 16; ++a) {
            float c = cr[a], s = sr[a];
            float e = bias[n0 + 2 * a], o = bias[n0 + 2 * a + 1];
            vals[2 * a]     = br[2 * a]     + e * c - o * s;
            vals[2 * a + 1] = br[2 * a + 1] + e * s + o * c;
        }
    } else {
#pragma unroll
        for (int j = 0; j < 32; ++j) vals[j] = br[j] + bias[n0 + j];
    }
}

// ---------------------------------------------------------------------------
// Per-chunk state delta via MFMA: Delta[p][n] = sum_i coef_i*v[i][p]*K[i][n].
// grid = 2048 blocks, 256 threads (4 waves, p-bands of 16).
// ---------------------------------------------------------------------------
__global__ __launch_bounds__(256, 2)
void delta_kernel(const float* __restrict__ proj, const float* __restrict__ Bn,
                  const float* __restrict__ cosb, const float* __restrict__ sinb,
                  const float* __restrict__ ell, const float* __restrict__ wbuf,
                  const float* __restrict__ pubuf, const float* __restrict__ B_bias,
                  float* __restrict__ delta, float* __restrict__ rbuf) {
    __shared__ ushort KT[DS * CHK];   // [n][i] swizzled (16 KB)
    __shared__ ushort VT[HD * CHK];   // cV^T [p][i] swizzled (8 KB)
    int blk = blockIdx.x;
    int c = blk & (NC - 1);
    int h = (blk >> 5) & (NH - 1);
    int b = blk >> 10;
    int tid = threadIdx.x;
    size_t row0 = (size_t)b * S_LEN + c * CHK;
    size_t bh = (size_t)b * NH + h;
    int i = tid >> 2, q4 = tid & 3;

    size_t so = bh * S_LEN + c * CHK + i;
    float llast = ell[bh * S_LEN + c * CHK + CHK - 1];
    float u = wbuf[so];
    if (c * CHK + i < S_LEN - 1) u += pubuf[so + 1];
    float coef = expf(llast - ell[so]) * u;
    if (tid == 0) {
        float base = (c == 0) ? 0.f : ell[bh * S_LEN + c * CHK - 1];
        rbuf[blk] = expf(llast - base);
    }
    // K^T build
    {
        int n0 = q4 * 32;
        float vals[32];
        build_vals32(vals, Bn + (row0 + i) * DS + n0, B_bias + h * DS,
                     cosb + (row0 + i) * NA + q4 * 16, sinb + (row0 + i) * NA + q4 * 16,
                     n0, q4 < 2);
#pragma unroll
        for (int j = 0; j < 32; ++j) {
            int n = n0 + j;
            KT[n * 64 + (((i >> 3) ^ (n & 7)) << 3) + (i & 7)] = f2bf(vals[j]);
        }
    }
    // cV^T build
    {
        int p0 = q4 * 16;
        const float* vr = proj + (row0 + i) * PDIM + OFF_V + h * HD + p0;
#pragma unroll
        for (int j = 0; j < 16; ++j) {
            int p = p0 + j;
            VT[p * 64 + (((i >> 3) ^ (p & 7)) << 3) + (i & 7)] = f2bf(vr[j] * coef);
        }
    }
    __syncthreads();
    int wv = tid >> 6, ln = tid & 63, rl = ln & 15, kg = ln >> 4;
    int pA = wv * 16 + rl;
    s8v aV[2];
#pragma unroll
    for (int ks = 0; ks < 2; ++ks)
        aV[ks] = *(const s8v*)&VT[pA * 64 + (((ks * 4 + kg) ^ (pA & 7)) << 3)];
    f4v dacc[8];
#pragma unroll
    for (int nt = 0; nt < 8; ++nt) dacc[nt] = f4v{0.f, 0.f, 0.f, 0.f};
#pragma unroll
    for (int nt = 0; nt < 8; ++nt) {
        int nB = nt * 16 + rl;
#pragma unroll
        for (int ks = 0; ks < 2; ++ks) {
            s8v bK = *(const s8v*)&KT[nB * 64 + (((ks * 4 + kg) ^ (nB & 7)) << 3)];
            dacc[nt] = __builtin_amdgcn_mfma_f32_16x16x32_bf16(aV[ks], bK, dacc[nt], 0, 0, 0);
        }
    }
    float* dp = delta + (bh * NC + c) * (size_t)(HD * DS);
#pragma unroll
    for (int nt = 0; nt < 8; ++nt) {
        int n = nt * 16 + rl;
#pragma unroll
        for (int r = 0; r < 4; ++r) {
            int p = wv * 16 + kg * 4 + r;
            dp[p * DS + n] = dacc[nt][r];
        }
    }
}

// ---------------------------------------------------------------------------
// Sequential chunk-state propagation (unchanged).
// ---------------------------------------------------------------------------
__global__ __launch_bounds__(256)
void state_prop(float* __restrict__ delta, const float* __restrict__ rbuf) {
    size_t bh = blockIdx.x;
    int tid = threadIdx.x;
    float4 st[8];
#pragma unroll
    for (int k = 0; k < 8; ++k) st[k] = float4{0.f, 0.f, 0.f, 0.f};
    for (int c = 0; c < NC; ++c) {
        float* dp = delta + (bh * NC + c) * (size_t)(HD * DS);
        float r = rbuf[bh * NC + c];
#pragma unroll
        for (int k = 0; k < 8; ++k) {
            int off = k * 1024 + tid * 4;
            float4 d = *(const float4*)(dp + off);
            float4 s = st[k];
            *(float4*)(dp + off) = s;
            st[k].x = fmaf(r, s.x, d.x);
            st[k].y = fmaf(r, s.y, d.y);
            st[k].z = fmaf(r, s.z, d.z);
            st[k].w = fmaf(r, s.w, d.w);
        }
    }
}

// ---------------------------------------------------------------------------
// Per-chunk output via MFMA: y = (masked QK^T)V + d_t*(Q S^T) + D*v.
// grid = 2048 blocks, 256 threads (4 waves, t-bands of 16). LDS 49 KB.
// ---------------------------------------------------------------------------
__global__ __launch_bounds__(256, 2)
void out_kernel(const float* __restrict__ proj, const float* __restrict__ Bn,
                const float* __restrict__ Cn, const float* __restrict__ cosb,
                const float* __restrict__ sinb, const float* __restrict__ ell,
                const float* __restrict__ wbuf, const float* __restrict__ pubuf,
                const float* __restrict__ B_bias, const float* __restrict__ C_bias,
                const float* __restrict__ D_param, const float* __restrict__ delta,
                float* __restrict__ y) {
    __shared__ ushort Qb[CHK * DS];   // [t][n] swizzled (16 KB)
    __shared__ ushort Kb[CHK * DS];   // [s][n] swizzled; reused as S[p][n] (16 KB)
    __shared__ ushort VTb[HD * CHK];  // V^T [p][t] swizzled (8 KB)
    __shared__ ushort PTb[CHK * CHK]; // P~ [t][s] swizzled (8 KB)
    __shared__ float s_ell[CHK], s_u[CHK], s_w[CHK], s_d[CHK];
    int blk = blockIdx.x;
    int c = blk & (NC - 1);
    int h = (blk >> 5) & (NH - 1);
    int b = blk >> 10;
    int tid = threadIdx.x;
    size_t row0 = (size_t)b * S_LEN + c * CHK;
    size_t bh = (size_t)b * NH + h;

    // prefetch state_in(c) [p][n] fp32 (32 floats/thread)
    const float* sp0 = delta + (bh * NC + c) * (size_t)(HD * DS)
                       + (size_t)(tid >> 2) * DS + (tid & 3) * 32;
    float4 sreg[8];
#pragma unroll
    for (int j = 0; j < 8; ++j) sreg[j] = ((const float4*)sp0)[j];

    int t = tid >> 2, q4 = tid & 3;
    // Q build (Cn + rotated C_bias), row-major swizzled
    {
        int n0 = q4 * 32;
        float vals[32];
        build_vals32(vals, Cn + (row0 + t) * DS + n0, C_bias + h * DS,
                     cosb + (row0 + t) * NA + q4 * 16, sinb + (row0 + t) * NA + q4 * 16,
                     n0, q4 < 2);
#pragma unroll
        for (int j = 0; j < 4; ++j) {
            int cc = (q4 * 4 + j) ^ (t & 7);
            *(uint4*)&Qb[t * 128 + cc * 8] = pack8(&vals[j * 8]);
        }
    }
    // K build (Bn + rotated B_bias)
    {
        int n0 = q4 * 32;
        float vals[32];
        build_vals32(vals, Bn + (row0 + t) * DS + n0, B_bias + h * DS,
                     cosb + (row0 + t) * NA + q4 * 16, sinb + (row0 + t) * NA + q4 * 16,
                     n0, q4 < 2);
#pragma unroll
        for (int j = 0; j < 4; ++j) {
            int cc = (q4 * 4 + j) ^ (t & 7);
            *(uint4*)&Kb[t * 128 + cc * 8] = pack8(&vals[j * 8]);
        }
    }
    // V^T build
    {
        int p0 = q4 * 16;
        const float* vr = proj + (row0 + t) * PDIM + OFF_V + h * HD + p0;
#pragma unroll
        for (int j = 0; j < 16; ++j) {
            int p = p0 + j;
            VTb[p * 64 + (((t >> 3) ^ (p & 7)) << 3) + (t & 7)] = f2bf(vr[j]);
        }
    }
    if (tid < CHK) {
        int tt = tid;
        size_t so = bh * S_LEN + c * CHK + tt;
        float lt = ell[so];
        s_ell[tt] = lt;
        float wv_ = wbuf[so];
        s_w[tt] = wv_;
        float u = wv_;
        if (c * CHK + tt < S_LEN - 1) u += pubuf[so + 1];
        s_u[tt] = u;
        float base = (c == 0) ? 0.f : ell[bh * S_LEN + c * CHK - 1];
        s_d[tt] = expf(lt - base);
    }
    __syncthreads();

    int wv = tid >> 6, ln = tid & 63, rl = ln & 15, kg = ln >> 4;
    int tA = wv * 16 + rl;
    // QK^T
    s8v aQ[4];
#pragma unroll
    for (int kc = 0; kc < 4; ++kc)
        aQ[kc] = *(const s8v*)&Qb[tA * 128 + (((kc * 4 + kg) ^ (tA & 7)) << 3)];
    f4v pacc[4];
#pragma unroll
    for (int st = 0; st < 4; ++st) pacc[st] = f4v{0.f, 0.f, 0.f, 0.f};
#pragma unroll
    for (int st = 0; st < 4; ++st) {
        int sB = st * 16 + rl;
#pragma unroll
        for (int kc = 0; kc < 4; ++kc) {
            s8v bK = *(const s8v*)&Kb[sB * 128 + (((kc * 4 + kg) ^ (sB & 7)) << 3)];
            pacc[st] = __builtin_amdgcn_mfma_f32_16x16x32_bf16(aQ[kc], bK, pacc[st], 0, 0, 0);
        }
    }
    // mask + write P~ [t][s] bf16
#pragma unroll
    for (int st = 0; st < 4; ++st) {
        int s = st * 16 + rl;
#pragma unroll
        for (int r = 0; r < 4; ++r) {
            int t2 = wv * 16 + kg * 4 + r;
            float m;
            if (s < t2)       m = expf(s_ell[t2] - s_ell[s]) * s_u[s];
            else if (s == t2) m = s_w[t2];
            else              m = 0.f;
            PTb[t2 * 64 + (((s >> 3) ^ (t2 & 7)) << 3) + (s & 7)] = f2bf(pacc[st][r] * m);
        }
    }
    __syncthreads();
    // write S (bf16 swizzled) into Kb space
    {
        int p = tid >> 2, nq = tid & 3;
        float fv[32];
#pragma unroll
        for (int j = 0; j < 8; ++j) *(float4*)&fv[j * 4] = sreg[j];
#pragma unroll
        for (int j = 0; j < 4; ++j) {
            int cc = (nq * 4 + j) ^ (p & 7);
            *(uint4*)&Kb[p * 128 + cc * 8] = pack8(&fv[j * 8]);
        }
    }
    __syncthreads();
    // y1 = P~ V, y2 = Q S^T
    s8v aP[2];
#pragma unroll
    for (int ks = 0; ks < 2; ++ks)
        aP[ks] = *(const s8v*)&PTb[tA * 64 + (((ks * 4 + kg) ^ (tA & 7)) << 3)];
    f4v y1[4], y2[4];
#pragma unroll
    for (int pt = 0; pt < 4; ++pt) { y1[pt] = f4v{0.f,0.f,0.f,0.f}; y2[pt] = f4v{0.f,0.f,0.f,0.f}; }
#pragma unroll
    for (int pt = 0; pt < 4; ++pt) {
        int pB = pt * 16 + rl;
#pragma unroll
        for (int ks = 0; ks < 2; ++ks) {
            s8v bV = *(const s8v*)&VTb[pB * 64 + (((ks * 4 + kg) ^ (pB & 7)) << 3)];
            y1[pt] = __builtin_amdgcn_mfma_f32_16x16x32_bf16(aP[ks], bV, y1[pt], 0, 0, 0);
        }
#pragma unroll
        for (int kc = 0; kc < 4; ++kc) {
            s8v bS = *(const s8v*)&Kb[pB * 128 + (((kc * 4 + kg) ^ (pB & 7)) << 3)];
            y2[pt] = __builtin_amdgcn_mfma_f32_16x16x32_bf16(aQ[kc], bS, y2[pt], 0, 0, 0);
        }
    }
    // output
    float Dp = D_param[h];
#pragma unroll
    for (int pt = 0; pt < 4; ++pt) {
#pragma unroll
        for (int r = 0; r < 4; ++r) {
            int t2 = wv * 16 + kg * 4 + r;
            int p = pt * 16 + rl;
            float v = proj[(row0 + t2) * PDIM + OFF_V + h * HD + p];
            y[(row0 + t2) * DI + h * HD + p] = y1[pt][r] + s_d[t2] * y2[pt][r] + Dp * v;
        }
    }
}

// ---------------------------------------------------------------------------
// y RMSNorm * out_norm_w * silu(z) -> bf16 swizzled.
// ---------------------------------------------------------------------------
__global__ __launch_bounds__(256)
void ynorm_kernel(const float* __restrict__ y, const float* __restrict__ proj,
                  const float* __restrict__ w, ushort* __restrict__ ybf) {
    size_t row = blockIdx.x;
    int tid = threadIdx.x;
    const float* yr = y + row * (size_t)DI;
    float4 v0 = *(const float4*)(yr + tid * 8);
    float4 v1 = *(const float4*)(yr + tid * 8 + 4);
    float ss = v0.x * v0.x + v0.y * v0.y + v0.z * v0.z + v0.w * v0.w +
               v1.x * v1.x + v1.y * v1.y + v1.z * v1.z + v1.w * v1.w;
#pragma unroll
    for (int off = 32; off >= 1; off >>= 1) ss += __shfl_xor(ss, off);
    __shared__ float red[4];
    if ((tid & 63) == 0) red[tid >> 6] = ss;
    __syncthreads();
    float tot = red[0] + red[1] + red[2] + red[3];
    float rinv = 1.f / sqrtf(tot * (1.f / 2048.f) + 1e-5f);
    const float* zr = proj + row * (size_t)PDIM + OFF_Z;
    float4 z0 = *(const float4*)(zr + tid * 8);
    float4 z1 = *(const float4*)(zr + tid * 8 + 4);
    float4 w0 = *(const float4*)(w + tid * 8);
    float4 w1 = *(const float4*)(w + tid * 8 + 4);
    float yv[8] = {v0.x, v0.y, v0.z, v0.w, v1.x, v1.y, v1.z, v1.w};
    float zv[8] = {z0.x, z0.y, z0.z, z0.w, z1.x, z1.y, z1.z, z1.w};
    float wv[8] = {w0.x, w0.y, w0.z, w0.w, w1.x, w1.y, w1.z, w1.w};
    ushort u[8];
#pragma unroll
    for (int e = 0; e < 8; ++e) {
        float sil = zv[e] / (1.f + expf(-zv[e]));
        u[e] = f2bf(yv[e] * rinv * wv[e] * sil);
    }
    int dstc = (tid & ~7) | ((tid & 7) ^ ((int)row & 7));
    uint4 o;
    o.x = (unsigned)u[0] | ((unsigned)u[1] << 16);
    o.y = (unsigned)u[2] | ((unsigned)u[3] << 16);
    o.z = (unsigned)u[4] | ((unsigned)u[5] << 16);
    o.w = (unsigned)u[6] | ((unsigned)u[7] << 16);
    *(uint4*)(ybf + row * (size_t)DI + dstc * 8) = o;
}

// ---------------------------------------------------------------------------
extern "C" void kernel_launch(void* const* d_in, const int* in_sizes, int n_in,
                              void* d_out, int out_size, void* d_ws, size_t ws_size,
                              hipStream_t stream) {
    const float* x          = (const float*)d_in[0];
    const float* W_in       = (const float*)d_in[1];
    const float* dt_bias    = (const float*)d_in[2];
    const float* B_norm_w   = (const float*)d_in[3];
    const float* C_norm_w   = (const float*)d_in[4];
    const float* B_bias     = (const float*)d_in[5];
    const float* C_bias     = (const float*)d_in[6];
    const float* D_param    = (const float*)d_in[7];
    const float* out_norm_w = (const float*)d_in[8];
    const float* W_out      = (const float*)d_in[9];
    float* out = (float*)d_out;

    const size_t M = (size_t)NBATCH * S_LEN;  // 4096
    float* ws = (float*)d_ws;
    size_t off = 0;
    float* proj  = ws + off; off += M * PDIM;
    float* cosb  = ws + off; off += M * NA;
    float* sinb  = ws + off; off += M * NA;
    float* Bn    = ws + off; off += M * DS;
    float* Cn    = ws + off; off += M * DS;
    float* ell   = ws + off; off += (size_t)NBATCH * NH * S_LEN;
    float* wbuf  = ws + off; off += (size_t)NBATCH * NH * S_LEN;
    float* pubuf = ws + off; off += (size_t)NBATCH * NH * S_LEN;
    float* delta = ws + off; off += (size_t)NBATCH * NH * NC * HD * DS;
    float* rbuf  = ws + off; off += (size_t)NBATCH * NH * NC;
    float* y     = ws + off; off += M * DI;
    ushort* xbf  = (ushort*)(ws + off); off += M * DMODEL / 2;
    ushort* wibf = (ushort*)(ws + off); off += (size_t)PDIM * DMODEL / 2;
    ushort* wobf = (ushort*)(ws + off); off += (size_t)DMODEL * DI / 2;
    ushort* ybf  = (ushort*)(ws + off); off += M * DI / 2;

    // 0) fp32 -> bf16 (swizzled) conversions
    {
        int nc_x  = (int)(M * DMODEL / 8);
        int nc_wi = PDIM * DMODEL / 8;
        int nc_wo = DMODEL * DI / 8;
        f2bf_swz<<<dim3((nc_x + 255) / 256), 256, 0, stream>>>(x, xbf, nc_x, 7);
        f2bf_swz<<<dim3((nc_wi + 255) / 256), 256, 0, stream>>>(W_in, wibf, nc_wi, 7);
        f2bf_swz<<<dim3((nc_wo + 255) / 256), 256, 0, stream>>>(W_out, wobf, nc_wo, 8);
    }
    // 1) proj = x @ W_in^T
    gemm_bf16<<<dim3((PDIM / 128) * (int)(M / 128)), 256, 0, stream>>>(xbf, wibf, proj, (int)M, PDIM, DMODEL);
    // 2) phase cumsum -> cos/sin
    phase_kernel<<<dim3(NBATCH * NA), 256, 0, stream>>>(proj, cosb, sinb);
    // 3) per-row prep
    prep_kernel<<<dim3((int)M), 128, 0, stream>>>(proj, dt_bias, B_norm_w, C_norm_w,
                                                  cosb, sinb, Bn, Cn, ell, wbuf, pubuf);
    // 4) cumsum of log-decay
    lcum_kernel<<<dim3(NBATCH * NH), 256, 0, stream>>>(ell);
    // 5) per-chunk delta states (MFMA)
    delta_kernel<<<dim3(NBATCH * NH * NC), 256, 0, stream>>>(proj, Bn, cosb, sinb, ell,
                                                             wbuf, pubuf, B_bias, delta, rbuf);
    // 6) chunk-state propagation
    state_prop<<<dim3(NBATCH * NH), 256, 0, stream>>>(delta, rbuf);
    // 7) per-chunk outputs (MFMA)
    out_kernel<<<dim3(NBATCH * NH * NC), 256, 0, stream>>>(proj, Bn, Cn, cosb, sinb, ell,
                                                           wbuf, pubuf, B_bias, C_bias,
                                                           D_param, delta, y);
    // 8) y = rmsnorm(y)*w*silu(z) -> bf16 swizzled
    ynorm_kernel<<<dim3((int)M), 256, 0, stream>>>(y, proj, out_norm_w, ybf);
    // 9) out = y @ W_out^T
    gemm_bf16<<<dim3((DMODEL / 128) * (int)(M / 128)), 256, 0, stream>>>(ybf, wobf, out, (int)M, DMODEL, DI);
}